// Round 8
// baseline (363.020 us; speedup 1.0000x reference)
//
#include <hip/hip_runtime.h>
#include <stdint.h>

// ---------- types ----------
typedef __attribute__((ext_vector_type(8))) __bf16 bf16x8;
typedef __attribute__((ext_vector_type(4))) float floatx4;

#define DEV __device__ __forceinline__

DEV unsigned short f2bf(float f) {
    union { float f; unsigned u; } uf; uf.f = f;
    unsigned u = uf.u;
    unsigned r = (u + 0x7fffu + ((u >> 16) & 1u)) >> 16;  // RNE
    return (unsigned short)r;
}

DEV float fast_exp2(float x) {
#if __has_builtin(__builtin_amdgcn_exp2f)
    return __builtin_amdgcn_exp2f(x);
#else
    return exp2f(x);
#endif
}

DEV unsigned pack_trunc2(float lo, float hi) {
    // (trunc_bf16(hi) << 16) | trunc_bf16(lo) in one v_perm_b32
    return __builtin_amdgcn_perm(__float_as_uint(hi), __float_as_uint(lo), 0x07060302u);
}

DEV void async16(const void* g, void* l) {
    __builtin_amdgcn_global_load_lds(
        (const __attribute__((address_space(1))) void*)g,
        (__attribute__((address_space(3))) void*)l, 16, 0, 0);
}

// ---------- merged cast: x (8M f32), 4 weights (4M f32), 3 biases ----------
__global__ void cast_all_kernel(const float* __restrict__ x,
                                const float* __restrict__ Wq, const float* __restrict__ Wk,
                                const float* __restrict__ Wv, const float* __restrict__ Wo,
                                const float* __restrict__ bq, const float* __restrict__ bk,
                                const float* __restrict__ bv,
                                unsigned short* __restrict__ xb,
                                unsigned short* __restrict__ wqkv,
                                unsigned short* __restrict__ wo,
                                float* __restrict__ bqkv) {
    const int NX = 2097152;   // float4s in x
    const int NW = 262144;    // float4s per weight
    int i = blockIdx.x * blockDim.x + threadIdx.x;
    if (i < NX) {
        float4 v = reinterpret_cast<const float4*>(x)[i];
        ushort4 o;
        o.x = f2bf(v.x); o.y = f2bf(v.y); o.z = f2bf(v.z); o.w = f2bf(v.w);
        reinterpret_cast<ushort4*>(xb)[i] = o;
        return;
    }
    int j = i - NX;
    if (j < 4 * NW) {
        int seg = j >> 18, off = j & (NW - 1);
        const float* src = (seg == 0) ? Wq : (seg == 1) ? Wk : (seg == 2) ? Wv : Wo;
        unsigned short* dst = (seg < 3) ? (wqkv + seg * 1048576) : wo;
        float4 v = reinterpret_cast<const float4*>(src)[off];
        ushort4 o;
        o.x = f2bf(v.x); o.y = f2bf(v.y); o.z = f2bf(v.z); o.w = f2bf(v.w);
        reinterpret_cast<ushort4*>(dst)[off] = o;
        return;
    }
    int k = j - 4 * NW;
    if (k < 768) {  // 3 x 1024 floats of bias as float4
        int seg = k >> 8, off = k & 255;
        const float* src = (seg == 0) ? bq : (seg == 1) ? bk : bv;
        reinterpret_cast<float4*>(bqkv)[k] = reinterpret_cast<const float4*>(src)[off];
    }
}

// ---------- 128x128 GEMM, C = A(MxK) * B(NxK)^T, bf16 in, fp32 acc ----------
// Grid: x = bm, y = bn (8 consecutive blocks -> 8 XCDs share one B-tile).
// QKV epilogue. bn<8: Q (scaled by Dh^-0.5*log2e), 8..15: K, 16..23: V
// V^T gets virtual-key perm v=(a&15)*4+(a>>4) per 64-key block (round-0
// verified pairing with the LDS-P read path in attn).
// Epilogues CHUNKED into two 64-row passes -> sT fits inside the 32 KB
// staging region -> LDS 32768 B; launch_bounds(256,5) caps VGPR at 102
// -> 5 blocks/CU (was 34.8 KB LDS + unconstrained VGPR -> 3-4 blocks/CU).
template <int MODE>
__global__ __launch_bounds__(256, 5)
void gemm128(const unsigned short* __restrict__ A,   // M x K  (K-contig)
             const unsigned short* __restrict__ B,   // N x K  (K-contig)
             const float* __restrict__ bias,         // N
             unsigned short* __restrict__ q_ws,
             unsigned short* __restrict__ k_ws,
             unsigned short* __restrict__ v_ws,
             float* __restrict__ fout) {
    constexpr int K = 1024;
    __shared__ alignas(16) unsigned short smem[16384];  // 32 KB exactly
    unsigned short* sA = smem;             // 128*64
    unsigned short* sB = smem + 128 * 64;  // 128*64
    unsigned short* sT = smem;             // 64*136 chunk staging (aliases sA/sB)

    const int tid = threadIdx.x;
    const int w = tid >> 6, lane = tid & 63, quad = lane >> 4, l16 = lane & 15;
    const int wr = w >> 1, wc = w & 1;
    const int bm = blockIdx.x, bn = blockIdx.y;
    const int arow0 = bm * 128, brow0 = bn * 128;

    floatx4 acc[4][4];
#pragma unroll
    for (int i = 0; i < 4; i++)
#pragma unroll
        for (int j = 0; j < 4; j++) acc[i][j] = (floatx4){0.f, 0.f, 0.f, 0.f};

    for (int k0 = 0; k0 < K; k0 += 64) {
#pragma unroll
        for (int i = 0; i < 4; i++) {
            int cb = i * 256 + w * 64;
            int ci = cb + lane;
            int row = ci >> 3, cl = ci & 7, cs = cl ^ (row & 7);
            async16(A + (size_t)(arow0 + row) * K + k0 + cs * 8, (char*)sA + cb * 16);
            async16(B + (size_t)(brow0 + row) * K + k0 + cs * 8, (char*)sB + cb * 16);
        }
        __syncthreads();
#pragma unroll
        for (int kk = 0; kk < 2; kk++) {
            bf16x8 aF[4], bF[4];
#pragma unroll
            for (int i = 0; i < 4; i++) {
                int row = wr * 64 + i * 16 + l16;
                int c = kk * 4 + quad, ph = c ^ (row & 7);
                aF[i] = *reinterpret_cast<const bf16x8*>(sA + row * 64 + ph * 8);
            }
#pragma unroll
            for (int j = 0; j < 4; j++) {
                int row = wc * 64 + j * 16 + l16;
                int c = kk * 4 + quad, ph = c ^ (row & 7);
                bF[j] = *reinterpret_cast<const bf16x8*>(sB + row * 64 + ph * 8);
            }
#pragma unroll
            for (int i = 0; i < 4; i++)
#pragma unroll
                for (int j = 0; j < 4; j++)
                    acc[i][j] = __builtin_amdgcn_mfma_f32_16x16x32_bf16(
                        aF[i], bF[j], acc[i][j], 0, 0, 0);
        }
        __syncthreads();
    }

    if (bn < 16) {
        // Q or K: two 64-row chunks through sT (wr==ch waves write their rows)
        unsigned short* dst = (bn < 8) ? q_ws : k_ws;
        const float sc = (bn < 8) ? 0.18033688f : 1.0f;  // Dh^-0.5 * log2(e) for Q
        const int nnbase = (bn & 7) * 128;
        const int c0 = (tid & 15) * 8;
        const int h = (nnbase + c0) >> 6, d = c0 & 63;
#pragma unroll
        for (int ch = 0; ch < 2; ch++) {
            if (ch) __syncthreads();
            if (wr == ch) {
#pragma unroll
                for (int j = 0; j < 4; j++) {
                    const int c = wc * 64 + j * 16 + l16;
                    const float bia = bias[brow0 + c];
#pragma unroll
                    for (int i = 0; i < 4; i++) {
                        int s_loc = i * 16 + quad * 4;
#pragma unroll
                        for (int r = 0; r < 4; r++)
                            sT[(s_loc + r) * 136 + c] = f2bf((acc[i][j][r] + bia) * sc);
                    }
                }
            }
            __syncthreads();
#pragma unroll
            for (int it = 0; it < 4; it++) {
                int s_loc = (tid >> 4) + it * 16;
                int s = arow0 + ch * 64 + s_loc;
                int bb = s >> 11, s4 = s & 2047;
                uint4 vdat = *reinterpret_cast<const uint4*>(sT + s_loc * 136 + c0);
                *reinterpret_cast<uint4*>(
                    dst + ((size_t)(bb * 16 + h) * 2048 + s4) * 64 + d) = vdat;
            }
        }
    } else {
        // V: two 64-col chunks (wc==ch waves write); round-0 verified perm
        // v = (quad*4+r)*4 + i within each 64-key block.
        const int bb2 = bm >> 4, blk = bm & 15;
        const int chunk = tid & 15;
#pragma unroll
        for (int ch = 0; ch < 2; ch++) {
            if (ch) __syncthreads();
            if (wc == ch) {
#pragma unroll
                for (int j = 0; j < 4; j++) {
                    const int c = wc * 64 + j * 16 + l16;   // global col
                    const int cl = j * 16 + l16;            // chunk-local col
                    const float bia = bias[brow0 + c];
#pragma unroll
                    for (int i = 0; i < 4; i++) {
#pragma unroll
                        for (int r = 0; r < 4; r++) {
                            int v = wr * 64 + (quad * 4 + r) * 4 + i;
                            sT[cl * 136 + v] = f2bf(acc[i][j][r] + bia);
                        }
                    }
                }
            }
            __syncthreads();
#pragma unroll
            for (int it = 0; it < 4; it++) {
                int rl = (tid >> 4) + it * 16;       // chunk-local col 0..63
                int h2 = (bn - 16) * 2 + ch, d2 = rl;
                ushort4 lo = *reinterpret_cast<const ushort4*>(sT + rl * 136 + chunk * 8);
                ushort4 hi = *reinterpret_cast<const ushort4*>(sT + rl * 136 + chunk * 8 + 4);
                size_t off = ((size_t)(bb2 * 16 + h2) * 64 + d2) * 2048 + blk * 128 + chunk * 8;
                *reinterpret_cast<ushort4*>(v_ws + off) = lo;
                *reinterpret_cast<ushort4*>(v_ws + off + 4) = hi;
            }
        }
    }
}

// ---------- out-proj GEMM: 128x64 tile, grid (64,16) = 1024 blocks ----------
// M=8192, N=1024, K=1024. 4 blocks/CU fully resident, 16 waves/CU.
__global__ __launch_bounds__(256)
void gemm_oproj(const unsigned short* __restrict__ A,   // 8192 x 1024
                const unsigned short* __restrict__ Bw,  // 1024 x 1024
                const float* __restrict__ bias,         // 1024
                float* __restrict__ fout) {
    constexpr int K = 1024;
    __shared__ alignas(16) unsigned short smem[192 * 64];  // 24 KB
    unsigned short* sA = smem;             // 128*64
    unsigned short* sB = smem + 128 * 64;  // 64*64
    float* sT32 = reinterpret_cast<float*>(smem);  // 64*68 f32 = 17408 B

    const int tid = threadIdx.x;
    const int w = tid >> 6, lane = tid & 63, quad = lane >> 4, l16 = lane & 15;
    const int wr = w >> 1, wc = w & 1;
    const int bm = blockIdx.x, bn = blockIdx.y;
    const int arow0 = bm * 128, brow0 = bn * 64;

    floatx4 acc[4][2];
#pragma unroll
    for (int i = 0; i < 4; i++)
#pragma unroll
        for (int j = 0; j < 2; j++) acc[i][j] = (floatx4){0.f, 0.f, 0.f, 0.f};

    for (int k0 = 0; k0 < K; k0 += 64) {
#pragma unroll
        for (int i = 0; i < 4; i++) {  // A: 1024 chunks, 4/thread
            int ci = i * 256 + tid;
            int row = ci >> 3, cs = (ci & 7) ^ (row & 7);
            async16(A + (size_t)(arow0 + row) * K + k0 + cs * 8, (char*)sA + ci * 16);
        }
#pragma unroll
        for (int i = 0; i < 2; i++) {  // B: 512 chunks, 2/thread
            int ci = i * 256 + tid;
            int row = ci >> 3, cs = (ci & 7) ^ (row & 7);
            async16(Bw + (size_t)(brow0 + row) * K + k0 + cs * 8, (char*)sB + ci * 16);
        }
        __syncthreads();
#pragma unroll
        for (int kk = 0; kk < 2; kk++) {
            bf16x8 aF[4], bF[2];
#pragma unroll
            for (int i = 0; i < 4; i++) {
                int row = wr * 64 + i * 16 + l16;
                int ph = (kk * 4 + quad) ^ (row & 7);
                aF[i] = *reinterpret_cast<const bf16x8*>(sA + row * 64 + ph * 8);
            }
#pragma unroll
            for (int j = 0; j < 2; j++) {
                int row = wc * 32 + j * 16 + l16;
                int ph = (kk * 4 + quad) ^ (row & 7);
                bF[j] = *reinterpret_cast<const bf16x8*>(sB + row * 64 + ph * 8);
            }
#pragma unroll
            for (int i = 0; i < 4; i++)
#pragma unroll
                for (int j = 0; j < 2; j++)
                    acc[i][j] = __builtin_amdgcn_mfma_f32_16x16x32_bf16(
                        aF[i], bF[j], acc[i][j], 0, 0, 0);
        }
        __syncthreads();
    }

    // epilogue: fp32 out via LDS transpose, two 64-row chunks
#pragma unroll
    for (int ch = 0; ch < 2; ch++) {
        if (ch) __syncthreads();
        if (wr == ch) {
#pragma unroll
            for (int j = 0; j < 2; j++) {
                const int c = wc * 32 + j * 16 + l16;
                const float bia = bias[brow0 + c];
#pragma unroll
                for (int i = 0; i < 4; i++) {
                    int s_loc = i * 16 + quad * 4;
#pragma unroll
                    for (int r = 0; r < 4; r++)
                        sT32[(s_loc + r) * 68 + c] = acc[i][j][r] + bia;
                }
            }
        }
        __syncthreads();
        const int cpos = (tid & 15) * 4;
#pragma unroll
        for (int it = 0; it < 4; it++) {
            int s_loc = (tid >> 4) + it * 16;
            int grow = arow0 + ch * 64 + s_loc;
            float4 vv = *reinterpret_cast<const float4*>(sT32 + s_loc * 68 + cpos);
            *reinterpret_cast<float4*>(fout + (size_t)grow * 1024 + brow0 + cpos) = vv;
        }
    }
}

// ---------- flash attention: one block = (bh, 128 q rows) ----------
// Round-6 body (best measured: 87.9 us) + T5 setprio around MFMA clusters
// (blocks are phase-independent -> scheduler has something to arbitrate).
// LDS 40 KB, 4 blocks/CU.
__global__ __launch_bounds__(256, 4)
void attn_kernel(const unsigned short* __restrict__ q_ws,
                 const unsigned short* __restrict__ k_ws,
                 const unsigned short* __restrict__ v_ws,
                 unsigned short* __restrict__ o_ws) {
    __shared__ alignas(16) unsigned short smem[20480];  // 40 KB
    // [0,4096): sK buf0   [4096,8192): sK buf1
    // [8192,12288): sVt buf0  [12288,16384): sVt buf1
    // [16384,20480): sP, wave w at +w*1024 (16 q-rows x 64 vkeys, chunk-XOR)

    const int tid = threadIdx.x;
    const int w = tid >> 6, lane = tid & 63, quad = lane >> 4, l16 = lane & 15;
    // XCD-affinity remap: all 16 q-blocks of one bh land on one XCD (id%8)
    const int id = blockIdx.x;
    const int bh = (id >> 7) * 8 + (id & 7);
    const int q0 = ((id >> 3) & 15) * 128;
    const size_t base = (size_t)bh * 2048 * 64;

    unsigned short* sPw = smem + 16384 + w * 1024;

    bf16x8 aQ[2][2];
#pragma unroll
    for (int g = 0; g < 2; g++) {
        int qrow = q0 + g * 64 + w * 16 + l16;
        const unsigned short* qp = q_ws + base + (size_t)qrow * 64 + quad * 8;
        aQ[g][0] = *reinterpret_cast<const bf16x8*>(qp);
        aQ[g][1] = *reinterpret_cast<const bf16x8*>(qp + 32);
    }

    // staging: 64x64 tile = 512 chunks of 16B; 2 chunks per thread for K and V
    const unsigned short* kg[2];
    const unsigned short* vg[2];
    int loff[2];
#pragma unroll
    for (int it = 0; it < 2; it++) {
        int ci = it * 256 + tid;
        int row = ci >> 3, cl = ci & 7, cs = cl ^ (row & 7);
        kg[it] = k_ws + base + (size_t)row * 64 + cs * 8;
        vg[it] = v_ws + base + (size_t)row * 2048 + cs * 8;
        loff[it] = ci * 8;  // shorts
    }

    const __bf16 one = (__bf16)1.0f;
    const bf16x8 vOnes = {one, one, one, one, one, one, one, one};

    floatx4 oAcc[2][4], rsAcc[2];
#pragma unroll
    for (int g = 0; g < 2; g++) {
#pragma unroll
        for (int j = 0; j < 4; j++) oAcc[g][j] = (floatx4){0.f, 0.f, 0.f, 0.f};
        rsAcc[g] = (floatx4){0.f, 0.f, 0.f, 0.f};
    }

    // prologue: stage tile 0 into buf 0
    {
#pragma unroll
        for (int it = 0; it < 2; it++) {
            async16(kg[it], smem + loff[it]);
            async16(vg[it], smem + 8192 + loff[it]);
        }
    }

    const int xr = l16 & 7;
    const int offw0 = l16 * 64 + (((2 * quad) ^ xr) << 3);
    const int offw1 = l16 * 64 + (((2 * quad + 1) ^ xr) << 3);
    const int offr0 = l16 * 64 + ((quad ^ xr) << 3);
    const int offr1 = l16 * 64 + (((4 + quad) ^ xr) << 3);

    for (int t = 0; t < 32; t++) {
        const int b = t & 1;
        const unsigned short* sK = smem + b * 4096;
        const unsigned short* sVt = smem + 8192 + b * 4096;
        __syncthreads();  // tile t staged (vmcnt drain); buf b^1 free for reuse

        if (t < 31) {
            const int kv0 = (t + 1) * 64;
            unsigned short* dK = smem + (b ^ 1) * 4096;
            unsigned short* dV = smem + 8192 + (b ^ 1) * 4096;
#pragma unroll
            for (int it = 0; it < 2; it++) {
                async16(kg[it] + (size_t)kv0 * 64, dK + loff[it]);
                async16(vg[it] + kv0, dV + loff[it]);
            }
        }

        // S'^T = K Q'^T for BOTH groups, sharing each aK load.
        floatx4 s0[4], s1[4];
#pragma unroll
        for (int j = 0; j < 4; j++) {
            s0[j] = (floatx4){0.f, 0.f, 0.f, 0.f};
            s1[j] = (floatx4){0.f, 0.f, 0.f, 0.f};
        }
        __builtin_amdgcn_s_setprio(1);
#pragma unroll
        for (int kk = 0; kk < 2; kk++) {
#pragma unroll
            for (int j = 0; j < 4; j++) {
                int krow = j * 16 + l16;
                int ph = (kk * 4 + quad) ^ (krow & 7);
                bf16x8 aK = *reinterpret_cast<const bf16x8*>(sK + krow * 64 + ph * 8);
                s0[j] = __builtin_amdgcn_mfma_f32_16x16x32_bf16(aK, aQ[0][kk], s0[j], 0, 0, 0);
                s1[j] = __builtin_amdgcn_mfma_f32_16x16x32_bf16(aK, aQ[1][kk], s1[j], 0, 0, 0);
            }
        }
        __builtin_amdgcn_s_setprio(0);

        // group 0: exp, pack, write sP0
#pragma unroll
        for (int j = 0; j < 4; j++)
#pragma unroll
            for (int r = 0; r < 4; r++) s0[j][r] = fast_exp2(s0[j][r]);
        {
            uint4 w0, w1;
            w0.x = pack_trunc2(s0[0][0], s0[1][0]);
            w0.y = pack_trunc2(s0[2][0], s0[3][0]);
            w0.z = pack_trunc2(s0[0][1], s0[1][1]);
            w0.w = pack_trunc2(s0[2][1], s0[3][1]);
            w1.x = pack_trunc2(s0[0][2], s0[1][2]);
            w1.y = pack_trunc2(s0[2][2], s0[3][2]);
            w1.z = pack_trunc2(s0[0][3], s0[1][3]);
            w1.w = pack_trunc2(s0[2][3], s0[3][3]);
            *reinterpret_cast<uint4*>(sPw + offw0) = w0;
            *reinterpret_cast<uint4*>(sPw + offw1) = w1;
        }

        // group 1 exp pass covers the sP0 write latency
#pragma unroll
        for (int j = 0; j < 4; j++)
#pragma unroll
            for (int r = 0; r < 4; r++) s1[j][r] = fast_exp2(s1[j][r]);

        asm volatile("s_waitcnt lgkmcnt(0)" ::: "memory");
        __builtin_amdgcn_sched_barrier(0);

        // group 0: read aP, PV, rowsum
        {
            bf16x8 aPa = *reinterpret_cast<const bf16x8*>(sPw + offr0);
            bf16x8 aPb = *reinterpret_cast<const bf16x8*>(sPw + offr1);
            __builtin_amdgcn_s_setprio(1);
#pragma unroll
            for (int jd = 0; jd < 4; jd++) {
                int drow = jd * 16 + l16;
                int ph0 = quad ^ (drow & 7);
                bf16x8 bVa = *reinterpret_cast<const bf16x8*>(sVt + drow * 64 + ph0 * 8);
                oAcc[0][jd] = __builtin_amdgcn_mfma_f32_16x16x32_bf16(aPa, bVa, oAcc[0][jd], 0, 0, 0);
                int ph1 = (4 + quad) ^ (drow & 7);
                bf16x8 bVb = *reinterpret_cast<const bf16x8*>(sVt + drow * 64 + ph1 * 8);
                oAcc[0][jd] = __builtin_amdgcn_mfma_f32_16x16x32_bf16(aPb, bVb, oAcc[0][jd], 0, 0, 0);
            }
            rsAcc[0] = __builtin_amdgcn_mfma_f32_16x16x32_bf16(aPa, vOnes, rsAcc[0], 0, 0, 0);
            rsAcc[0] = __builtin_amdgcn_mfma_f32_16x16x32_bf16(aPb, vOnes, rsAcc[0], 0, 0, 0);
            __builtin_amdgcn_s_setprio(0);
        }

        // group 1: pack, write sP (after group-0 aP reads: same-wave DS FIFO
        // + C++ may-alias ordering keep read-before-write), covered by PV0
        {
            uint4 w0, w1;
            w0.x = pack_trunc2(s1[0][0], s1[1][0]);
            w0.y = pack_trunc2(s1[2][0], s1[3][0]);
            w0.z = pack_trunc2(s1[0][1], s1[1][1]);
            w0.w = pack_trunc2(s1[2][1], s1[3][1]);
            w1.x = pack_trunc2(s1[0][2], s1[1][2]);
            w1.y = pack_trunc2(s1[2][2], s1[3][2]);
            w1.z = pack_trunc2(s1[0][3], s1[1][3]);
            w1.w = pack_trunc2(s1[2][3], s1[3][3]);
            *reinterpret_cast<uint4*>(sPw + offw0) = w0;
            *reinterpret_cast<uint4*>(sPw + offw1) = w1;
        }

        asm volatile("s_waitcnt lgkmcnt(0)" ::: "memory");
        __builtin_amdgcn_sched_barrier(0);

        // group 1: read aP, PV, rowsum
        {
            bf16x8 aPa = *reinterpret_cast<const bf16x8*>(sPw + offr0);
            bf16x8 aPb = *reinterpret_cast<const bf16x8*>(sPw + offr1);
            __builtin_amdgcn_s_setprio(1);
#pragma unroll
            for (int jd = 0; jd < 4; jd++) {
                int drow = jd * 16 + l16;
                int ph0 = quad ^ (drow & 7);
                bf16x8 bVa = *reinterpret_cast<const bf16x8*>(sVt + drow * 64 + ph0 * 8);
                oAcc[1][jd] = __builtin_amdgcn_mfma_f32_16x16x32_bf16(aPa, bVa, oAcc[1][jd], 0, 0, 0);
                int ph1 = (4 + quad) ^ (drow & 7);
                bf16x8 bVb = *reinterpret_cast<const bf16x8*>(sVt + drow * 64 + ph1 * 8);
                oAcc[1][jd] = __builtin_amdgcn_mfma_f32_16x16x32_bf16(aPb, bVb, oAcc[1][jd], 0, 0, 0);
            }
            rsAcc[1] = __builtin_amdgcn_mfma_f32_16x16x32_bf16(aPa, vOnes, rsAcc[1], 0, 0, 0);
            rsAcc[1] = __builtin_amdgcn_mfma_f32_16x16x32_bf16(aPb, vOnes, rsAcc[1], 0, 0, 0);
            __builtin_amdgcn_s_setprio(0);
        }
    }

    // epilogue: rsAcc[g][r] = row sum for q=g*64+w*16+quad*4+r (repl. l16)
    const int bb = bh >> 4, h = bh & 15;
#pragma unroll
    for (int g = 0; g < 2; g++) {
        float inv[4];
#pragma unroll
        for (int r = 0; r < 4; r++) inv[r] = 1.0f / rsAcc[g][r];
#pragma unroll
        for (int jd = 0; jd < 4; jd++) {
            int d = jd * 16 + l16;
#pragma unroll
            for (int r = 0; r < 4; r++) {
                int s = q0 + g * 64 + w * 16 + quad * 4 + r;
                float v = oAcc[g][jd][r] * inv[r];
                o_ws[((size_t)bb * 2048 + s) * 1024 + h * 64 + d] = f2bf(v);
            }
        }
    }
}

// ---------- launch ----------
extern "C" void kernel_launch(void* const* d_in, const int* in_sizes, int n_in,
                              void* d_out, int out_size, void* d_ws, size_t ws_size,
                              hipStream_t stream) {
    const float* x  = (const float*)d_in[0];
    const float* Wq = (const float*)d_in[1];
    const float* bq = (const float*)d_in[2];
    const float* Wk = (const float*)d_in[3];
    const float* bk = (const float*)d_in[4];
    const float* Wv = (const float*)d_in[5];
    const float* bv = (const float*)d_in[6];
    const float* Wo = (const float*)d_in[7];
    const float* bo = (const float*)d_in[8];
    float* out = (float*)d_out;

    char* ws = (char*)d_ws;
    unsigned short* xb   = (unsigned short*)(ws);                       // 16 MB
    unsigned short* wqkv = (unsigned short*)(ws + (16ull << 20));       // 6 MB
    unsigned short* wo   = (unsigned short*)(ws + (22ull << 20));       // 2 MB
    float*          bqkv = (float*)(ws + (24ull << 20));                // 12 KB
    unsigned short* q_ws = (unsigned short*)(ws + (25ull << 20));       // 16 MB
    unsigned short* k_ws = (unsigned short*)(ws + (41ull << 20));       // 16 MB
    unsigned short* v_ws = (unsigned short*)(ws + (57ull << 20));       // 16 MB
    unsigned short* o_ws = xb;  // alias: x_bf dead after QKV GEMM

    // one cast kernel: 2097152 (x) + 1048576 (W) + 768 (bias) float4 slots
    cast_all_kernel<<<12291, 256, 0, stream>>>(x, Wq, Wk, Wv, Wo, bq, bk, bv,
                                               xb, wqkv, wo, bqkv);

    gemm128<0><<<dim3(64, 24), 256, 0, stream>>>(xb, wqkv, bqkv, q_ws, k_ws, v_ws, nullptr);
    attn_kernel<<<1024, 256, 0, stream>>>(q_ws, k_ws, v_ws, o_ws);
    gemm_oproj<<<dim3(64, 16), 256, 0, stream>>>(o_ws, wo, bo, out);
}

// Round 9
// 266.489 us; speedup vs baseline: 1.3622x; 1.3622x over previous
//
#include <hip/hip_runtime.h>
#include <stdint.h>

// ---------- types ----------
typedef __attribute__((ext_vector_type(8))) __bf16 bf16x8;
typedef __attribute__((ext_vector_type(4))) float floatx4;

#define DEV __device__ __forceinline__

DEV unsigned short f2bf(float f) {
    union { float f; unsigned u; } uf; uf.f = f;
    unsigned u = uf.u;
    unsigned r = (u + 0x7fffu + ((u >> 16) & 1u)) >> 16;  // RNE
    return (unsigned short)r;
}

DEV float fast_exp2(float x) {
#if __has_builtin(__builtin_amdgcn_exp2f)
    return __builtin_amdgcn_exp2f(x);
#else
    return exp2f(x);
#endif
}

DEV unsigned pack_trunc2(float lo, float hi) {
    // (trunc_bf16(hi) << 16) | trunc_bf16(lo) in one v_perm_b32
    return __builtin_amdgcn_perm(__float_as_uint(hi), __float_as_uint(lo), 0x07060302u);
}

DEV void async16(const void* g, void* l) {
    __builtin_amdgcn_global_load_lds(
        (const __attribute__((address_space(1))) void*)g,
        (__attribute__((address_space(3))) void*)l, 16, 0, 0);
}

// ---------- merged cast: x (8M f32), 4 weights (4M f32), 3 biases ----------
__global__ void cast_all_kernel(const float* __restrict__ x,
                                const float* __restrict__ Wq, const float* __restrict__ Wk,
                                const float* __restrict__ Wv, const float* __restrict__ Wo,
                                const float* __restrict__ bq, const float* __restrict__ bk,
                                const float* __restrict__ bv,
                                unsigned short* __restrict__ xb,
                                unsigned short* __restrict__ wqkv,
                                unsigned short* __restrict__ wo,
                                float* __restrict__ bqkv) {
    const int NX = 2097152;   // float4s in x
    const int NW = 262144;    // float4s per weight
    int i = blockIdx.x * blockDim.x + threadIdx.x;
    if (i < NX) {
        float4 v = reinterpret_cast<const float4*>(x)[i];
        ushort4 o;
        o.x = f2bf(v.x); o.y = f2bf(v.y); o.z = f2bf(v.z); o.w = f2bf(v.w);
        reinterpret_cast<ushort4*>(xb)[i] = o;
        return;
    }
    int j = i - NX;
    if (j < 4 * NW) {
        int seg = j >> 18, off = j & (NW - 1);
        const float* src = (seg == 0) ? Wq : (seg == 1) ? Wk : (seg == 2) ? Wv : Wo;
        unsigned short* dst = (seg < 3) ? (wqkv + seg * 1048576) : wo;
        float4 v = reinterpret_cast<const float4*>(src)[off];
        ushort4 o;
        o.x = f2bf(v.x); o.y = f2bf(v.y); o.z = f2bf(v.z); o.w = f2bf(v.w);
        reinterpret_cast<ushort4*>(dst)[off] = o;
        return;
    }
    int k = j - 4 * NW;
    if (k < 768) {  // 3 x 1024 floats of bias as float4
        int seg = k >> 8, off = k & 255;
        const float* src = (seg == 0) ? bq : (seg == 1) ? bk : bv;
        reinterpret_cast<float4*>(bqkv)[k] = reinterpret_cast<const float4*>(src)[off];
    }
}

// ---------- 128x128 GEMM, C = A(MxK) * B(NxK)^T, bf16 in, fp32 acc ----------
// ROUND-6 EXACT VERSION (R8's launch_bounds(256,5)+32KB variant spilled:
// VGPR 48 arch + scratch, WRITE_SIZE 176 MB, 170 us. Unconstrained VGPR +
// 34.8 KB LDS = 4 blocks/CU, no spills — keep.)
// Grid: x = bm, y = bn (8 consecutive blocks -> 8 XCDs share one B-tile).
// bn<8: Q (scaled by Dh^-0.5*log2e), 8..15: K, 16..23: V
// V^T gets virtual-key perm v=(a&15)*4+(a>>4) per 64-key block.
template <int MODE>
__global__ __launch_bounds__(256)
void gemm128(const unsigned short* __restrict__ A,   // M x K  (K-contig)
             const unsigned short* __restrict__ B,   // N x K  (K-contig)
             const float* __restrict__ bias,         // N
             unsigned short* __restrict__ q_ws,
             unsigned short* __restrict__ k_ws,
             unsigned short* __restrict__ v_ws,
             float* __restrict__ fout) {
    constexpr int K = 1024;
    __shared__ alignas(16) unsigned short smem[128 * 136];  // sA+sB / sT union
    unsigned short* sA = smem;             // 128*64
    unsigned short* sB = smem + 128 * 64;  // 128*64
    unsigned short* sT = smem;             // 128*136 (transpose staging, bf16)

    const int tid = threadIdx.x;
    const int w = tid >> 6, lane = tid & 63, quad = lane >> 4, l16 = lane & 15;
    const int wr = w >> 1, wc = w & 1;
    const int bm = blockIdx.x, bn = blockIdx.y;
    const int arow0 = bm * 128, brow0 = bn * 128;

    floatx4 acc[4][4];
#pragma unroll
    for (int i = 0; i < 4; i++)
#pragma unroll
        for (int j = 0; j < 4; j++) acc[i][j] = (floatx4){0.f, 0.f, 0.f, 0.f};

    for (int k0 = 0; k0 < K; k0 += 64) {
#pragma unroll
        for (int i = 0; i < 4; i++) {
            int cb = i * 256 + w * 64;
            int ci = cb + lane;
            int row = ci >> 3, cl = ci & 7, cs = cl ^ (row & 7);
            async16(A + (size_t)(arow0 + row) * K + k0 + cs * 8, (char*)sA + cb * 16);
            async16(B + (size_t)(brow0 + row) * K + k0 + cs * 8, (char*)sB + cb * 16);
        }
        __syncthreads();
#pragma unroll
        for (int kk = 0; kk < 2; kk++) {
            bf16x8 aF[4], bF[4];
#pragma unroll
            for (int i = 0; i < 4; i++) {
                int row = wr * 64 + i * 16 + l16;
                int c = kk * 4 + quad, ph = c ^ (row & 7);
                aF[i] = *reinterpret_cast<const bf16x8*>(sA + row * 64 + ph * 8);
            }
#pragma unroll
            for (int j = 0; j < 4; j++) {
                int row = wc * 64 + j * 16 + l16;
                int c = kk * 4 + quad, ph = c ^ (row & 7);
                bF[j] = *reinterpret_cast<const bf16x8*>(sB + row * 64 + ph * 8);
            }
#pragma unroll
            for (int i = 0; i < 4; i++)
#pragma unroll
                for (int j = 0; j < 4; j++)
                    acc[i][j] = __builtin_amdgcn_mfma_f32_16x16x32_bf16(
                        aF[i], bF[j], acc[i][j], 0, 0, 0);
        }
        __syncthreads();
    }

    if (bn < 16) {
        // Q or K via LDS transpose -> coalesced 16B stores into (bh, s, d)
        unsigned short* dst = (bn < 8) ? q_ws : k_ws;
        const float sc = (bn < 8) ? 0.18033688f : 1.0f;  // Dh^-0.5 * log2(e) for Q
#pragma unroll
        for (int j = 0; j < 4; j++) {
            const int c = wc * 64 + j * 16 + l16;
            const float bia = bias[brow0 + c];
#pragma unroll
            for (int i = 0; i < 4; i++) {
                int s_loc = wr * 64 + i * 16 + quad * 4;
#pragma unroll
                for (int r = 0; r < 4; r++)
                    sT[(s_loc + r) * 136 + c] = f2bf((acc[i][j][r] + bia) * sc);
            }
        }
        __syncthreads();
        const int nnbase = (bn & 7) * 128;
        const int c0 = (tid & 15) * 8;
        const int h = (nnbase + c0) >> 6, d = c0 & 63;
#pragma unroll
        for (int it = 0; it < 8; it++) {
            int s_loc = (tid >> 4) + it * 16;
            int s = arow0 + s_loc;
            int bb = s >> 11, s4 = s & 2047;
            uint4 vdat = *reinterpret_cast<const uint4*>(sT + s_loc * 136 + c0);
            *reinterpret_cast<uint4*>(
                dst + ((size_t)(bb * 16 + h) * 2048 + s4) * 64 + d) = vdat;
        }
    } else {
        // V: transpose via LDS, store (bh, d, s_virtual) coalesced.
        // ROUND-0 VERIFIED 64-key virtual perm: s_local = wr*64 + a,
        // a = i*16+quad*4+r,  v = (a&15)*4 + (a>>4) = (quad*4+r)*4 + i
#pragma unroll
        for (int j = 0; j < 4; j++) {
            const int c = wc * 64 + j * 16 + l16;  // block-local col 0..127
            const float bia = bias[brow0 + c];
#pragma unroll
            for (int i = 0; i < 4; i++) {
#pragma unroll
                for (int r = 0; r < 4; r++) {
                    int v = wr * 64 + (quad * 4 + r) * 4 + i;
                    sT[c * 136 + v] = f2bf(acc[i][j][r] + bia);
                }
            }
        }
        __syncthreads();
        const int bb = bm >> 4, blk = bm & 15;
        const int chunk = tid & 15;
#pragma unroll
        for (int it = 0; it < 8; it++) {
            int row = (tid >> 4) + it * 16;   // block-local col = h*64+d part
            int h = (bn - 16) * 2 + (row >> 6), d = row & 63;
            ushort4 lo = *reinterpret_cast<const ushort4*>(sT + row * 136 + chunk * 8);
            ushort4 hi = *reinterpret_cast<const ushort4*>(sT + row * 136 + chunk * 8 + 4);
            size_t off = ((size_t)(bb * 16 + h) * 64 + d) * 2048 + blk * 128 + chunk * 8;
            *reinterpret_cast<ushort4*>(v_ws + off) = lo;
            *reinterpret_cast<ushort4*>(v_ws + off + 4) = hi;
        }
    }
}

// ---------- out-proj GEMM: 128x64 tile, grid (64,16) = 1024 blocks ----------
// M=8192, N=1024, K=1024. 4 blocks/CU fully resident, 16 waves/CU.
__global__ __launch_bounds__(256)
void gemm_oproj(const unsigned short* __restrict__ A,   // 8192 x 1024
                const unsigned short* __restrict__ Bw,  // 1024 x 1024
                const float* __restrict__ bias,         // 1024
                float* __restrict__ fout) {
    constexpr int K = 1024;
    __shared__ alignas(16) unsigned short smem[192 * 64];  // 24 KB
    unsigned short* sA = smem;             // 128*64
    unsigned short* sB = smem + 128 * 64;  // 64*64
    float* sT32 = reinterpret_cast<float*>(smem);  // 64*68 f32 = 17408 B

    const int tid = threadIdx.x;
    const int w = tid >> 6, lane = tid & 63, quad = lane >> 4, l16 = lane & 15;
    const int wr = w >> 1, wc = w & 1;
    const int bm = blockIdx.x, bn = blockIdx.y;
    const int arow0 = bm * 128, brow0 = bn * 64;

    floatx4 acc[4][2];
#pragma unroll
    for (int i = 0; i < 4; i++)
#pragma unroll
        for (int j = 0; j < 2; j++) acc[i][j] = (floatx4){0.f, 0.f, 0.f, 0.f};

    for (int k0 = 0; k0 < K; k0 += 64) {
#pragma unroll
        for (int i = 0; i < 4; i++) {  // A: 1024 chunks, 4/thread
            int ci = i * 256 + tid;
            int row = ci >> 3, cs = (ci & 7) ^ (row & 7);
            async16(A + (size_t)(arow0 + row) * K + k0 + cs * 8, (char*)sA + ci * 16);
        }
#pragma unroll
        for (int i = 0; i < 2; i++) {  // B: 512 chunks, 2/thread
            int ci = i * 256 + tid;
            int row = ci >> 3, cs = (ci & 7) ^ (row & 7);
            async16(Bw + (size_t)(brow0 + row) * K + k0 + cs * 8, (char*)sB + ci * 16);
        }
        __syncthreads();
#pragma unroll
        for (int kk = 0; kk < 2; kk++) {
            bf16x8 aF[4], bF[2];
#pragma unroll
            for (int i = 0; i < 4; i++) {
                int row = wr * 64 + i * 16 + l16;
                int ph = (kk * 4 + quad) ^ (row & 7);
                aF[i] = *reinterpret_cast<const bf16x8*>(sA + row * 64 + ph * 8);
            }
#pragma unroll
            for (int j = 0; j < 2; j++) {
                int row = wc * 32 + j * 16 + l16;
                int ph = (kk * 4 + quad) ^ (row & 7);
                bF[j] = *reinterpret_cast<const bf16x8*>(sB + row * 64 + ph * 8);
            }
#pragma unroll
            for (int i = 0; i < 4; i++)
#pragma unroll
                for (int j = 0; j < 2; j++)
                    acc[i][j] = __builtin_amdgcn_mfma_f32_16x16x32_bf16(
                        aF[i], bF[j], acc[i][j], 0, 0, 0);
        }
        __syncthreads();
    }

    // epilogue: fp32 out via LDS transpose, two 64-row chunks
#pragma unroll
    for (int ch = 0; ch < 2; ch++) {
        if (ch) __syncthreads();
        if (wr == ch) {
#pragma unroll
            for (int j = 0; j < 2; j++) {
                const int c = wc * 32 + j * 16 + l16;
                const float bia = bias[brow0 + c];
#pragma unroll
                for (int i = 0; i < 4; i++) {
                    int s_loc = i * 16 + quad * 4;
#pragma unroll
                    for (int r = 0; r < 4; r++)
                        sT32[(s_loc + r) * 68 + c] = acc[i][j][r] + bia;
                }
            }
        }
        __syncthreads();
        const int cpos = (tid & 15) * 4;
#pragma unroll
        for (int it = 0; it < 4; it++) {
            int s_loc = (tid >> 4) + it * 16;
            int grow = arow0 + ch * 64 + s_loc;
            float4 vv = *reinterpret_cast<const float4*>(sT32 + s_loc * 68 + cpos);
            *reinterpret_cast<float4*>(fout + (size_t)grow * 1024 + brow0 + cpos) = vv;
        }
    }
}

// ---------- flash attention: one block = (bh, 128 q rows) ----------
// ROUND-6 BODY (best measured: 87.9 us) + T5 setprio around MFMA clusters
// (the ONLY delta vs round 6; blocks phase-independent -> setprio regime).
// LDS 40 KB, 4 blocks/CU.
__global__ __launch_bounds__(256, 4)
void attn_kernel(const unsigned short* __restrict__ q_ws,
                 const unsigned short* __restrict__ k_ws,
                 const unsigned short* __restrict__ v_ws,
                 unsigned short* __restrict__ o_ws) {
    __shared__ alignas(16) unsigned short smem[20480];  // 40 KB
    // [0,4096): sK buf0   [4096,8192): sK buf1
    // [8192,12288): sVt buf0  [12288,16384): sVt buf1
    // [16384,20480): sP, wave w at +w*1024 (16 q-rows x 64 vkeys, chunk-XOR)

    const int tid = threadIdx.x;
    const int w = tid >> 6, lane = tid & 63, quad = lane >> 4, l16 = lane & 15;
    // XCD-affinity remap: all 16 q-blocks of one bh land on one XCD (id%8)
    const int id = blockIdx.x;
    const int bh = (id >> 7) * 8 + (id & 7);
    const int q0 = ((id >> 3) & 15) * 128;
    const size_t base = (size_t)bh * 2048 * 64;

    unsigned short* sPw = smem + 16384 + w * 1024;

    bf16x8 aQ[2][2];
#pragma unroll
    for (int g = 0; g < 2; g++) {
        int qrow = q0 + g * 64 + w * 16 + l16;
        const unsigned short* qp = q_ws + base + (size_t)qrow * 64 + quad * 8;
        aQ[g][0] = *reinterpret_cast<const bf16x8*>(qp);
        aQ[g][1] = *reinterpret_cast<const bf16x8*>(qp + 32);
    }

    // staging: 64x64 tile = 512 chunks of 16B; 2 chunks per thread for K and V
    const unsigned short* kg[2];
    const unsigned short* vg[2];
    int loff[2];
#pragma unroll
    for (int it = 0; it < 2; it++) {
        int ci = it * 256 + tid;
        int row = ci >> 3, cl = ci & 7, cs = cl ^ (row & 7);
        kg[it] = k_ws + base + (size_t)row * 64 + cs * 8;
        vg[it] = v_ws + base + (size_t)row * 2048 + cs * 8;
        loff[it] = ci * 8;  // shorts
    }

    const __bf16 one = (__bf16)1.0f;
    const bf16x8 vOnes = {one, one, one, one, one, one, one, one};

    floatx4 oAcc[2][4], rsAcc[2];
#pragma unroll
    for (int g = 0; g < 2; g++) {
#pragma unroll
        for (int j = 0; j < 4; j++) oAcc[g][j] = (floatx4){0.f, 0.f, 0.f, 0.f};
        rsAcc[g] = (floatx4){0.f, 0.f, 0.f, 0.f};
    }

    // prologue: stage tile 0 into buf 0
    {
#pragma unroll
        for (int it = 0; it < 2; it++) {
            async16(kg[it], smem + loff[it]);
            async16(vg[it], smem + 8192 + loff[it]);
        }
    }

    const int xr = l16 & 7;
    const int offw0 = l16 * 64 + (((2 * quad) ^ xr) << 3);
    const int offw1 = l16 * 64 + (((2 * quad + 1) ^ xr) << 3);
    const int offr0 = l16 * 64 + ((quad ^ xr) << 3);
    const int offr1 = l16 * 64 + (((4 + quad) ^ xr) << 3);

    for (int t = 0; t < 32; t++) {
        const int b = t & 1;
        const unsigned short* sK = smem + b * 4096;
        const unsigned short* sVt = smem + 8192 + b * 4096;
        __syncthreads();  // tile t staged (vmcnt drain); buf b^1 free for reuse

        if (t < 31) {
            const int kv0 = (t + 1) * 64;
            unsigned short* dK = smem + (b ^ 1) * 4096;
            unsigned short* dV = smem + 8192 + (b ^ 1) * 4096;
#pragma unroll
            for (int it = 0; it < 2; it++) {
                async16(kg[it] + (size_t)kv0 * 64, dK + loff[it]);
                async16(vg[it] + kv0, dV + loff[it]);
            }
        }

        // S'^T = K Q'^T for BOTH groups, sharing each aK load.
        floatx4 s0[4], s1[4];
#pragma unroll
        for (int j = 0; j < 4; j++) {
            s0[j] = (floatx4){0.f, 0.f, 0.f, 0.f};
            s1[j] = (floatx4){0.f, 0.f, 0.f, 0.f};
        }
        __builtin_amdgcn_s_setprio(1);
#pragma unroll
        for (int kk = 0; kk < 2; kk++) {
#pragma unroll
            for (int j = 0; j < 4; j++) {
                int krow = j * 16 + l16;
                int ph = (kk * 4 + quad) ^ (krow & 7);
                bf16x8 aK = *reinterpret_cast<const bf16x8*>(sK + krow * 64 + ph * 8);
                s0[j] = __builtin_amdgcn_mfma_f32_16x16x32_bf16(aK, aQ[0][kk], s0[j], 0, 0, 0);
                s1[j] = __builtin_amdgcn_mfma_f32_16x16x32_bf16(aK, aQ[1][kk], s1[j], 0, 0, 0);
            }
        }
        __builtin_amdgcn_s_setprio(0);

        // group 0: exp in place, pack, write sP
#pragma unroll
        for (int j = 0; j < 4; j++)
#pragma unroll
            for (int r = 0; r < 4; r++) s0[j][r] = fast_exp2(s0[j][r]);
        {
            uint4 w0, w1;
            w0.x = pack_trunc2(s0[0][0], s0[1][0]);
            w0.y = pack_trunc2(s0[2][0], s0[3][0]);
            w0.z = pack_trunc2(s0[0][1], s0[1][1]);
            w0.w = pack_trunc2(s0[2][1], s0[3][1]);
            w1.x = pack_trunc2(s0[0][2], s0[1][2]);
            w1.y = pack_trunc2(s0[2][2], s0[3][2]);
            w1.z = pack_trunc2(s0[0][3], s0[1][3]);
            w1.w = pack_trunc2(s0[2][3], s0[3][3]);
            *reinterpret_cast<uint4*>(sPw + offw0) = w0;
            *reinterpret_cast<uint4*>(sPw + offw1) = w1;
        }

        // group 1 exp pass covers the sP0 write latency
#pragma unroll
        for (int j = 0; j < 4; j++)
#pragma unroll
            for (int r = 0; r < 4; r++) s1[j][r] = fast_exp2(s1[j][r]);

        asm volatile("s_waitcnt lgkmcnt(0)" ::: "memory");
        __builtin_amdgcn_sched_barrier(0);

        // group 0: read aP, PV, rowsum
        {
            bf16x8 aPa = *reinterpret_cast<const bf16x8*>(sPw + offr0);
            bf16x8 aPb = *reinterpret_cast<const bf16x8*>(sPw + offr1);
            __builtin_amdgcn_s_setprio(1);
#pragma unroll
            for (int jd = 0; jd < 4; jd++) {
                int drow = jd * 16 + l16;
                int ph0 = quad ^ (drow & 7);
                bf16x8 bVa = *reinterpret_cast<const bf16x8*>(sVt + drow * 64 + ph0 * 8);
                oAcc[0][jd] = __builtin_amdgcn_mfma_f32_16x16x32_bf16(aPa, bVa, oAcc[0][jd], 0, 0, 0);
                int ph1 = (4 + quad) ^ (drow & 7);
                bf16x8 bVb = *reinterpret_cast<const bf16x8*>(sVt + drow * 64 + ph1 * 8);
                oAcc[0][jd] = __builtin_amdgcn_mfma_f32_16x16x32_bf16(aPb, bVb, oAcc[0][jd], 0, 0, 0);
            }
            rsAcc[0] = __builtin_amdgcn_mfma_f32_16x16x32_bf16(aPa, vOnes, rsAcc[0], 0, 0, 0);
            rsAcc[0] = __builtin_amdgcn_mfma_f32_16x16x32_bf16(aPb, vOnes, rsAcc[0], 0, 0, 0);
            __builtin_amdgcn_s_setprio(0);
        }

        // group 1: pack, write sP (after group-0 aP reads: same-wave DS FIFO
        // + C++ may-alias ordering keep read-before-write), covered by PV0
        {
            uint4 w0, w1;
            w0.x = pack_trunc2(s1[0][0], s1[1][0]);
            w0.y = pack_trunc2(s1[2][0], s1[3][0]);
            w0.z = pack_trunc2(s1[0][1], s1[1][1]);
            w0.w = pack_trunc2(s1[2][1], s1[3][1]);
            w1.x = pack_trunc2(s1[0][2], s1[1][2]);
            w1.y = pack_trunc2(s1[2][2], s1[3][2]);
            w1.z = pack_trunc2(s1[0][3], s1[1][3]);
            w1.w = pack_trunc2(s1[2][3], s1[3][3]);
            *reinterpret_cast<uint4*>(sPw + offw0) = w0;
            *reinterpret_cast<uint4*>(sPw + offw1) = w1;
        }

        asm volatile("s_waitcnt lgkmcnt(0)" ::: "memory");
        __builtin_amdgcn_sched_barrier(0);

        // group 1: read aP, PV, rowsum
        {
            bf16x8 aPa = *reinterpret_cast<const bf16x8*>(sPw + offr0);
            bf16x8 aPb = *reinterpret_cast<const bf16x8*>(sPw + offr1);
            __builtin_amdgcn_s_setprio(1);
#pragma unroll
            for (int jd = 0; jd < 4; jd++) {
                int drow = jd * 16 + l16;
                int ph0 = quad ^ (drow & 7);
                bf16x8 bVa = *reinterpret_cast<const bf16x8*>(sVt + drow * 64 + ph0 * 8);
                oAcc[1][jd] = __builtin_amdgcn_mfma_f32_16x16x32_bf16(aPa, bVa, oAcc[1][jd], 0, 0, 0);
                int ph1 = (4 + quad) ^ (drow & 7);
                bf16x8 bVb = *reinterpret_cast<const bf16x8*>(sVt + drow * 64 + ph1 * 8);
                oAcc[1][jd] = __builtin_amdgcn_mfma_f32_16x16x32_bf16(aPb, bVb, oAcc[1][jd], 0, 0, 0);
            }
            rsAcc[1] = __builtin_amdgcn_mfma_f32_16x16x32_bf16(aPa, vOnes, rsAcc[1], 0, 0, 0);
            rsAcc[1] = __builtin_amdgcn_mfma_f32_16x16x32_bf16(aPb, vOnes, rsAcc[1], 0, 0, 0);
            __builtin_amdgcn_s_setprio(0);
        }
    }

    // epilogue: rsAcc[g][r] = row sum for q=g*64+w*16+quad*4+r (repl. l16)
    const int bb = bh >> 4, h = bh & 15;
#pragma unroll
    for (int g = 0; g < 2; g++) {
        float inv[4];
#pragma unroll
        for (int r = 0; r < 4; r++) inv[r] = 1.0f / rsAcc[g][r];
#pragma unroll
        for (int jd = 0; jd < 4; jd++) {
            int d = jd * 16 + l16;
#pragma unroll
            for (int r = 0; r < 4; r++) {
                int s = q0 + g * 64 + w * 16 + quad * 4 + r;
                float v = oAcc[g][jd][r] * inv[r];
                o_ws[((size_t)bb * 2048 + s) * 1024 + h * 64 + d] = f2bf(v);
            }
        }
    }
}

// ---------- launch ----------
extern "C" void kernel_launch(void* const* d_in, const int* in_sizes, int n_in,
                              void* d_out, int out_size, void* d_ws, size_t ws_size,
                              hipStream_t stream) {
    const float* x  = (const float*)d_in[0];
    const float* Wq = (const float*)d_in[1];
    const float* bq = (const float*)d_in[2];
    const float* Wk = (const float*)d_in[3];
    const float* bk = (const float*)d_in[4];
    const float* Wv = (const float*)d_in[5];
    const float* bv = (const float*)d_in[6];
    const float* Wo = (const float*)d_in[7];
    const float* bo = (const float*)d_in[8];
    float* out = (float*)d_out;

    char* ws = (char*)d_ws;
    unsigned short* xb   = (unsigned short*)(ws);                       // 16 MB
    unsigned short* wqkv = (unsigned short*)(ws + (16ull << 20));       // 6 MB
    unsigned short* wo   = (unsigned short*)(ws + (22ull << 20));       // 2 MB
    float*          bqkv = (float*)(ws + (24ull << 20));                // 12 KB
    unsigned short* q_ws = (unsigned short*)(ws + (25ull << 20));       // 16 MB
    unsigned short* k_ws = (unsigned short*)(ws + (41ull << 20));       // 16 MB
    unsigned short* v_ws = (unsigned short*)(ws + (57ull << 20));       // 16 MB
    unsigned short* o_ws = xb;  // alias: x_bf dead after QKV GEMM

    // one cast kernel: 2097152 (x) + 1048576 (W) + 768 (bias) float4 slots
    cast_all_kernel<<<12291, 256, 0, stream>>>(x, Wq, Wk, Wv, Wo, bq, bk, bv,
                                               xb, wqkv, wo, bqkv);

    gemm128<0><<<dim3(64, 24), 256, 0, stream>>>(xb, wqkv, bqkv, q_ws, k_ws, v_ws, nullptr);
    attn_kernel<<<1024, 256, 0, stream>>>(q_ws, k_ws, v_ws, o_ws);
    gemm_oproj<<<dim3(64, 16), 256, 0, stream>>>(o_ws, wo, bo, out);
}

// Round 10
// 265.324 us; speedup vs baseline: 1.3682x; 1.0044x over previous
//
#include <hip/hip_runtime.h>
#include <stdint.h>

// ---------- types ----------
typedef __attribute__((ext_vector_type(8))) __bf16 bf16x8;
typedef __attribute__((ext_vector_type(4))) float floatx4;

#define DEV __device__ __forceinline__

DEV unsigned short f2bf(float f) {
    union { float f; unsigned u; } uf; uf.f = f;
    unsigned u = uf.u;
    unsigned r = (u + 0x7fffu + ((u >> 16) & 1u)) >> 16;  // RNE
    return (unsigned short)r;
}

DEV float fast_exp2(float x) {
#if __has_builtin(__builtin_amdgcn_exp2f)
    return __builtin_amdgcn_exp2f(x);
#else
    return exp2f(x);
#endif
}

DEV unsigned pack_trunc2(float lo, float hi) {
    // (trunc_bf16(hi) << 16) | trunc_bf16(lo) in one v_perm_b32
    return __builtin_amdgcn_perm(__float_as_uint(hi), __float_as_uint(lo), 0x07060302u);
}

DEV void async16(const void* g, void* l) {
    __builtin_amdgcn_global_load_lds(
        (const __attribute__((address_space(1))) void*)g,
        (__attribute__((address_space(3))) void*)l, 16, 0, 0);
}

// ---------- merged cast: x (8M f32), 4 weights (4M f32), 3 biases ----------
__global__ void cast_all_kernel(const float* __restrict__ x,
                                const float* __restrict__ Wq, const float* __restrict__ Wk,
                                const float* __restrict__ Wv, const float* __restrict__ Wo,
                                const float* __restrict__ bq, const float* __restrict__ bk,
                                const float* __restrict__ bv,
                                unsigned short* __restrict__ xb,
                                unsigned short* __restrict__ wqkv,
                                unsigned short* __restrict__ wo,
                                float* __restrict__ bqkv) {
    const int NX = 2097152;   // float4s in x
    const int NW = 262144;    // float4s per weight
    int i = blockIdx.x * blockDim.x + threadIdx.x;
    if (i < NX) {
        float4 v = reinterpret_cast<const float4*>(x)[i];
        ushort4 o;
        o.x = f2bf(v.x); o.y = f2bf(v.y); o.z = f2bf(v.z); o.w = f2bf(v.w);
        reinterpret_cast<ushort4*>(xb)[i] = o;
        return;
    }
    int j = i - NX;
    if (j < 4 * NW) {
        int seg = j >> 18, off = j & (NW - 1);
        const float* src = (seg == 0) ? Wq : (seg == 1) ? Wk : (seg == 2) ? Wv : Wo;
        unsigned short* dst = (seg < 3) ? (wqkv + seg * 1048576) : wo;
        float4 v = reinterpret_cast<const float4*>(src)[off];
        ushort4 o;
        o.x = f2bf(v.x); o.y = f2bf(v.y); o.z = f2bf(v.z); o.w = f2bf(v.w);
        reinterpret_cast<ushort4*>(dst)[off] = o;
        return;
    }
    int k = j - 4 * NW;
    if (k < 768) {  // 3 x 1024 floats of bias as float4
        int seg = k >> 8, off = k & 255;
        const float* src = (seg == 0) ? bq : (seg == 1) ? bk : bv;
        reinterpret_cast<float4*>(bqkv)[k] = reinterpret_cast<const float4*>(src)[off];
    }
}

// ---------- 128x128 GEMM, C = A(MxK) * B(NxK)^T, bf16 in, fp32 acc ----------
// ROUND-6 EXACT VERSION (R8's launch_bounds(256,5)+32KB variant spilled).
// Grid: x = bm, y = bn (8 consecutive blocks -> 8 XCDs share one B-tile).
// bn<8: Q (scaled by Dh^-0.5*log2e), 8..15: K, 16..23: V
// V^T gets virtual-key perm v=(a&15)*4+(a>>4) per 64-key block.
template <int MODE>
__global__ __launch_bounds__(256)
void gemm128(const unsigned short* __restrict__ A,   // M x K  (K-contig)
             const unsigned short* __restrict__ B,   // N x K  (K-contig)
             const float* __restrict__ bias,         // N
             unsigned short* __restrict__ q_ws,
             unsigned short* __restrict__ k_ws,
             unsigned short* __restrict__ v_ws,
             float* __restrict__ fout) {
    constexpr int K = 1024;
    __shared__ alignas(16) unsigned short smem[128 * 136];  // sA+sB / sT union
    unsigned short* sA = smem;             // 128*64
    unsigned short* sB = smem + 128 * 64;  // 128*64
    unsigned short* sT = smem;             // 128*136 (transpose staging, bf16)

    const int tid = threadIdx.x;
    const int w = tid >> 6, lane = tid & 63, quad = lane >> 4, l16 = lane & 15;
    const int wr = w >> 1, wc = w & 1;
    const int bm = blockIdx.x, bn = blockIdx.y;
    const int arow0 = bm * 128, brow0 = bn * 128;

    floatx4 acc[4][4];
#pragma unroll
    for (int i = 0; i < 4; i++)
#pragma unroll
        for (int j = 0; j < 4; j++) acc[i][j] = (floatx4){0.f, 0.f, 0.f, 0.f};

    for (int k0 = 0; k0 < K; k0 += 64) {
#pragma unroll
        for (int i = 0; i < 4; i++) {
            int cb = i * 256 + w * 64;
            int ci = cb + lane;
            int row = ci >> 3, cl = ci & 7, cs = cl ^ (row & 7);
            async16(A + (size_t)(arow0 + row) * K + k0 + cs * 8, (char*)sA + cb * 16);
            async16(B + (size_t)(brow0 + row) * K + k0 + cs * 8, (char*)sB + cb * 16);
        }
        __syncthreads();
#pragma unroll
        for (int kk = 0; kk < 2; kk++) {
            bf16x8 aF[4], bF[4];
#pragma unroll
            for (int i = 0; i < 4; i++) {
                int row = wr * 64 + i * 16 + l16;
                int c = kk * 4 + quad, ph = c ^ (row & 7);
                aF[i] = *reinterpret_cast<const bf16x8*>(sA + row * 64 + ph * 8);
            }
#pragma unroll
            for (int j = 0; j < 4; j++) {
                int row = wc * 64 + j * 16 + l16;
                int c = kk * 4 + quad, ph = c ^ (row & 7);
                bF[j] = *reinterpret_cast<const bf16x8*>(sB + row * 64 + ph * 8);
            }
#pragma unroll
            for (int i = 0; i < 4; i++)
#pragma unroll
                for (int j = 0; j < 4; j++)
                    acc[i][j] = __builtin_amdgcn_mfma_f32_16x16x32_bf16(
                        aF[i], bF[j], acc[i][j], 0, 0, 0);
        }
        __syncthreads();
    }

    if (bn < 16) {
        // Q or K via LDS transpose -> coalesced 16B stores into (bh, s, d)
        unsigned short* dst = (bn < 8) ? q_ws : k_ws;
        const float sc = (bn < 8) ? 0.18033688f : 1.0f;  // Dh^-0.5 * log2(e) for Q
#pragma unroll
        for (int j = 0; j < 4; j++) {
            const int c = wc * 64 + j * 16 + l16;
            const float bia = bias[brow0 + c];
#pragma unroll
            for (int i = 0; i < 4; i++) {
                int s_loc = wr * 64 + i * 16 + quad * 4;
#pragma unroll
                for (int r = 0; r < 4; r++)
                    sT[(s_loc + r) * 136 + c] = f2bf((acc[i][j][r] + bia) * sc);
            }
        }
        __syncthreads();
        const int nnbase = (bn & 7) * 128;
        const int c0 = (tid & 15) * 8;
        const int h = (nnbase + c0) >> 6, d = c0 & 63;
#pragma unroll
        for (int it = 0; it < 8; it++) {
            int s_loc = (tid >> 4) + it * 16;
            int s = arow0 + s_loc;
            int bb = s >> 11, s4 = s & 2047;
            uint4 vdat = *reinterpret_cast<const uint4*>(sT + s_loc * 136 + c0);
            *reinterpret_cast<uint4*>(
                dst + ((size_t)(bb * 16 + h) * 2048 + s4) * 64 + d) = vdat;
        }
    } else {
        // V: transpose via LDS, store (bh, d, s_virtual) coalesced.
        // ROUND-0 VERIFIED 64-key virtual perm: s_local = wr*64 + a,
        // a = i*16+quad*4+r,  v = (a&15)*4 + (a>>4) = (quad*4+r)*4 + i
#pragma unroll
        for (int j = 0; j < 4; j++) {
            const int c = wc * 64 + j * 16 + l16;  // block-local col 0..127
            const float bia = bias[brow0 + c];
#pragma unroll
            for (int i = 0; i < 4; i++) {
#pragma unroll
                for (int r = 0; r < 4; r++) {
                    int v = wr * 64 + (quad * 4 + r) * 4 + i;
                    sT[c * 136 + v] = f2bf(acc[i][j][r] + bia);
                }
            }
        }
        __syncthreads();
        const int bb = bm >> 4, blk = bm & 15;
        const int chunk = tid & 15;
#pragma unroll
        for (int it = 0; it < 8; it++) {
            int row = (tid >> 4) + it * 16;   // block-local col = h*64+d part
            int h = (bn - 16) * 2 + (row >> 6), d = row & 63;
            ushort4 lo = *reinterpret_cast<const ushort4*>(sT + row * 136 + chunk * 8);
            ushort4 hi = *reinterpret_cast<const ushort4*>(sT + row * 136 + chunk * 8 + 4);
            size_t off = ((size_t)(bb * 16 + h) * 64 + d) * 2048 + blk * 128 + chunk * 8;
            *reinterpret_cast<ushort4*>(v_ws + off) = lo;
            *reinterpret_cast<ushort4*>(v_ws + off + 4) = hi;
        }
    }
}

// ---------- out-proj GEMM: 128x64 tile, grid (64,16) = 1024 blocks ----------
// M=8192, N=1024, K=1024. 4+ blocks/CU fully resident, one generation.
__global__ __launch_bounds__(256)
void gemm_oproj(const unsigned short* __restrict__ A,   // 8192 x 1024
                const unsigned short* __restrict__ Bw,  // 1024 x 1024
                const float* __restrict__ bias,         // 1024
                float* __restrict__ fout) {
    constexpr int K = 1024;
    __shared__ alignas(16) unsigned short smem[192 * 64];  // 24 KB
    unsigned short* sA = smem;             // 128*64
    unsigned short* sB = smem + 128 * 64;  // 64*64
    float* sT32 = reinterpret_cast<float*>(smem);  // 64*68 f32 = 17408 B

    const int tid = threadIdx.x;
    const int w = tid >> 6, lane = tid & 63, quad = lane >> 4, l16 = lane & 15;
    const int wr = w >> 1, wc = w & 1;
    const int bm = blockIdx.x, bn = blockIdx.y;
    const int arow0 = bm * 128, brow0 = bn * 64;

    floatx4 acc[4][2];
#pragma unroll
    for (int i = 0; i < 4; i++)
#pragma unroll
        for (int j = 0; j < 2; j++) acc[i][j] = (floatx4){0.f, 0.f, 0.f, 0.f};

    for (int k0 = 0; k0 < K; k0 += 64) {
#pragma unroll
        for (int i = 0; i < 4; i++) {  // A: 1024 chunks, 4/thread
            int ci = i * 256 + tid;
            int row = ci >> 3, cs = (ci & 7) ^ (row & 7);
            async16(A + (size_t)(arow0 + row) * K + k0 + cs * 8, (char*)sA + ci * 16);
        }
#pragma unroll
        for (int i = 0; i < 2; i++) {  // B: 512 chunks, 2/thread
            int ci = i * 256 + tid;
            int row = ci >> 3, cs = (ci & 7) ^ (row & 7);
            async16(Bw + (size_t)(brow0 + row) * K + k0 + cs * 8, (char*)sB + ci * 16);
        }
        __syncthreads();
#pragma unroll
        for (int kk = 0; kk < 2; kk++) {
            bf16x8 aF[4], bF[2];
#pragma unroll
            for (int i = 0; i < 4; i++) {
                int row = wr * 64 + i * 16 + l16;
                int ph = (kk * 4 + quad) ^ (row & 7);
                aF[i] = *reinterpret_cast<const bf16x8*>(sA + row * 64 + ph * 8);
            }
#pragma unroll
            for (int j = 0; j < 2; j++) {
                int row = wc * 32 + j * 16 + l16;
                int ph = (kk * 4 + quad) ^ (row & 7);
                bF[j] = *reinterpret_cast<const bf16x8*>(sB + row * 64 + ph * 8);
            }
#pragma unroll
            for (int i = 0; i < 4; i++)
#pragma unroll
                for (int j = 0; j < 2; j++)
                    acc[i][j] = __builtin_amdgcn_mfma_f32_16x16x32_bf16(
                        aF[i], bF[j], acc[i][j], 0, 0, 0);
        }
        __syncthreads();
    }

    // epilogue: fp32 out via LDS transpose, two 64-row chunks
#pragma unroll
    for (int ch = 0; ch < 2; ch++) {
        if (ch) __syncthreads();
        if (wr == ch) {
#pragma unroll
            for (int j = 0; j < 2; j++) {
                const int c = wc * 32 + j * 16 + l16;
                const float bia = bias[brow0 + c];
#pragma unroll
                for (int i = 0; i < 4; i++) {
                    int s_loc = i * 16 + quad * 4;
#pragma unroll
                    for (int r = 0; r < 4; r++)
                        sT32[(s_loc + r) * 68 + c] = acc[i][j][r] + bia;
                }
            }
        }
        __syncthreads();
        const int cpos = (tid & 15) * 4;
#pragma unroll
        for (int it = 0; it < 4; it++) {
            int s_loc = (tid >> 4) + it * 16;
            int grow = arow0 + ch * 64 + s_loc;
            float4 vv = *reinterpret_cast<const float4*>(sT32 + s_loc * 68 + cpos);
            *reinterpret_cast<float4*>(fout + (size_t)grow * 1024 + brow0 + cpos) = vv;
        }
    }
}

// ---------- flash attention: one block = (bh, 128 q rows) ----------
// Round-9 body MINUS the two per-tile lgkmcnt(0)+sched_barrier(0) walls.
// sPw is strictly per-wave; same-wave DS ops execute in order and the
// compiler must order the may-aliasing write->read itself (auto lgkmcnt).
// Removing the walls lets the scheduler interleave exp/pack VALU and
// aP/bV loads with the QK/PV MFMA clusters across the whole tile.
// LDS 40 KB, 4 blocks/CU. T5 setprio kept (r9: +2%).
__global__ __launch_bounds__(256, 4)
void attn_kernel(const unsigned short* __restrict__ q_ws,
                 const unsigned short* __restrict__ k_ws,
                 const unsigned short* __restrict__ v_ws,
                 unsigned short* __restrict__ o_ws) {
    __shared__ alignas(16) unsigned short smem[20480];  // 40 KB
    // [0,4096): sK buf0   [4096,8192): sK buf1
    // [8192,12288): sVt buf0  [12288,16384): sVt buf1
    // [16384,20480): sP, wave w at +w*1024 (16 q-rows x 64 vkeys, chunk-XOR)

    const int tid = threadIdx.x;
    const int w = tid >> 6, lane = tid & 63, quad = lane >> 4, l16 = lane & 15;
    // XCD-affinity remap: all 16 q-blocks of one bh land on one XCD (id%8)
    const int id = blockIdx.x;
    const int bh = (id >> 7) * 8 + (id & 7);
    const int q0 = ((id >> 3) & 15) * 128;
    const size_t base = (size_t)bh * 2048 * 64;

    unsigned short* sPw = smem + 16384 + w * 1024;

    bf16x8 aQ[2][2];
#pragma unroll
    for (int g = 0; g < 2; g++) {
        int qrow = q0 + g * 64 + w * 16 + l16;
        const unsigned short* qp = q_ws + base + (size_t)qrow * 64 + quad * 8;
        aQ[g][0] = *reinterpret_cast<const bf16x8*>(qp);
        aQ[g][1] = *reinterpret_cast<const bf16x8*>(qp + 32);
    }

    // staging: 64x64 tile = 512 chunks of 16B; 2 chunks per thread for K and V
    const unsigned short* kg[2];
    const unsigned short* vg[2];
    int loff[2];
#pragma unroll
    for (int it = 0; it < 2; it++) {
        int ci = it * 256 + tid;
        int row = ci >> 3, cl = ci & 7, cs = cl ^ (row & 7);
        kg[it] = k_ws + base + (size_t)row * 64 + cs * 8;
        vg[it] = v_ws + base + (size_t)row * 2048 + cs * 8;
        loff[it] = ci * 8;  // shorts
    }

    const __bf16 one = (__bf16)1.0f;
    const bf16x8 vOnes = {one, one, one, one, one, one, one, one};

    floatx4 oAcc[2][4], rsAcc[2];
#pragma unroll
    for (int g = 0; g < 2; g++) {
#pragma unroll
        for (int j = 0; j < 4; j++) oAcc[g][j] = (floatx4){0.f, 0.f, 0.f, 0.f};
        rsAcc[g] = (floatx4){0.f, 0.f, 0.f, 0.f};
    }

    // prologue: stage tile 0 into buf 0
    {
#pragma unroll
        for (int it = 0; it < 2; it++) {
            async16(kg[it], smem + loff[it]);
            async16(vg[it], smem + 8192 + loff[it]);
        }
    }

    const int xr = l16 & 7;
    const int offw0 = l16 * 64 + (((2 * quad) ^ xr) << 3);
    const int offw1 = l16 * 64 + (((2 * quad + 1) ^ xr) << 3);
    const int offr0 = l16 * 64 + ((quad ^ xr) << 3);
    const int offr1 = l16 * 64 + (((4 + quad) ^ xr) << 3);

    for (int t = 0; t < 32; t++) {
        const int b = t & 1;
        const unsigned short* sK = smem + b * 4096;
        const unsigned short* sVt = smem + 8192 + b * 4096;
        __syncthreads();  // tile t staged (vmcnt drain); buf b^1 free for reuse

        if (t < 31) {
            const int kv0 = (t + 1) * 64;
            unsigned short* dK = smem + (b ^ 1) * 4096;
            unsigned short* dV = smem + 8192 + (b ^ 1) * 4096;
#pragma unroll
            for (int it = 0; it < 2; it++) {
                async16(kg[it] + (size_t)kv0 * 64, dK + loff[it]);
                async16(vg[it] + kv0, dV + loff[it]);
            }
        }

        // S'^T = K Q'^T for BOTH groups, sharing each aK load.
        floatx4 s0[4], s1[4];
#pragma unroll
        for (int j = 0; j < 4; j++) {
            s0[j] = (floatx4){0.f, 0.f, 0.f, 0.f};
            s1[j] = (floatx4){0.f, 0.f, 0.f, 0.f};
        }
        __builtin_amdgcn_s_setprio(1);
#pragma unroll
        for (int kk = 0; kk < 2; kk++) {
#pragma unroll
            for (int j = 0; j < 4; j++) {
                int krow = j * 16 + l16;
                int ph = (kk * 4 + quad) ^ (krow & 7);
                bf16x8 aK = *reinterpret_cast<const bf16x8*>(sK + krow * 64 + ph * 8);
                s0[j] = __builtin_amdgcn_mfma_f32_16x16x32_bf16(aK, aQ[0][kk], s0[j], 0, 0, 0);
                s1[j] = __builtin_amdgcn_mfma_f32_16x16x32_bf16(aK, aQ[1][kk], s1[j], 0, 0, 0);
            }
        }
        __builtin_amdgcn_s_setprio(0);

        // group 0: exp, pack, write sP0 (same-wave DS order: write < read)
#pragma unroll
        for (int j = 0; j < 4; j++)
#pragma unroll
            for (int r = 0; r < 4; r++) s0[j][r] = fast_exp2(s0[j][r]);
        {
            uint4 w0, w1;
            w0.x = pack_trunc2(s0[0][0], s0[1][0]);
            w0.y = pack_trunc2(s0[2][0], s0[3][0]);
            w0.z = pack_trunc2(s0[0][1], s0[1][1]);
            w0.w = pack_trunc2(s0[2][1], s0[3][1]);
            w1.x = pack_trunc2(s0[0][2], s0[1][2]);
            w1.y = pack_trunc2(s0[2][2], s0[3][2]);
            w1.z = pack_trunc2(s0[0][3], s0[1][3]);
            w1.w = pack_trunc2(s0[2][3], s0[3][3]);
            *reinterpret_cast<uint4*>(sPw + offw0) = w0;
            *reinterpret_cast<uint4*>(sPw + offw1) = w1;
        }

        // group 0: read aP0, PV0, rowsum0 (compiler orders DS ops; VALU of
        // group-1 exp/pack below is free to interleave into this region)
        {
            bf16x8 aPa = *reinterpret_cast<const bf16x8*>(sPw + offr0);
            bf16x8 aPb = *reinterpret_cast<const bf16x8*>(sPw + offr1);
            __builtin_amdgcn_s_setprio(1);
#pragma unroll
            for (int jd = 0; jd < 4; jd++) {
                int drow = jd * 16 + l16;
                int ph0 = quad ^ (drow & 7);
                bf16x8 bVa = *reinterpret_cast<const bf16x8*>(sVt + drow * 64 + ph0 * 8);
                oAcc[0][jd] = __builtin_amdgcn_mfma_f32_16x16x32_bf16(aPa, bVa, oAcc[0][jd], 0, 0, 0);
                int ph1 = (4 + quad) ^ (drow & 7);
                bf16x8 bVb = *reinterpret_cast<const bf16x8*>(sVt + drow * 64 + ph1 * 8);
                oAcc[0][jd] = __builtin_amdgcn_mfma_f32_16x16x32_bf16(aPb, bVb, oAcc[0][jd], 0, 0, 0);
            }
            rsAcc[0] = __builtin_amdgcn_mfma_f32_16x16x32_bf16(aPa, vOnes, rsAcc[0], 0, 0, 0);
            rsAcc[0] = __builtin_amdgcn_mfma_f32_16x16x32_bf16(aPb, vOnes, rsAcc[0], 0, 0, 0);
            __builtin_amdgcn_s_setprio(0);
        }

        // group 1: exp, pack, write sP1 (write after group-0 reads by
        // program order + may-alias; same-wave DS FIFO preserves it in HW)
#pragma unroll
        for (int j = 0; j < 4; j++)
#pragma unroll
            for (int r = 0; r < 4; r++) s1[j][r] = fast_exp2(s1[j][r]);
        {
            uint4 w0, w1;
            w0.x = pack_trunc2(s1[0][0], s1[1][0]);
            w0.y = pack_trunc2(s1[2][0], s1[3][0]);
            w0.z = pack_trunc2(s1[0][1], s1[1][1]);
            w0.w = pack_trunc2(s1[2][1], s1[3][1]);
            w1.x = pack_trunc2(s1[0][2], s1[1][2]);
            w1.y = pack_trunc2(s1[2][2], s1[3][2]);
            w1.z = pack_trunc2(s1[0][3], s1[1][3]);
            w1.w = pack_trunc2(s1[2][3], s1[3][3]);
            *reinterpret_cast<uint4*>(sPw + offw0) = w0;
            *reinterpret_cast<uint4*>(sPw + offw1) = w1;
        }

        // group 1: read aP1, PV1, rowsum1
        {
            bf16x8 aPa = *reinterpret_cast<const bf16x8*>(sPw + offr0);
            bf16x8 aPb = *reinterpret_cast<const bf16x8*>(sPw + offr1);
            __builtin_amdgcn_s_setprio(1);
#pragma unroll
            for (int jd = 0; jd < 4; jd++) {
                int drow = jd * 16 + l16;
                int ph0 = quad ^ (drow & 7);
                bf16x8 bVa = *reinterpret_cast<const bf16x8*>(sVt + drow * 64 + ph0 * 8);
                oAcc[1][jd] = __builtin_amdgcn_mfma_f32_16x16x32_bf16(aPa, bVa, oAcc[1][jd], 0, 0, 0);
                int ph1 = (4 + quad) ^ (drow & 7);
                bf16x8 bVb = *reinterpret_cast<const bf16x8*>(sVt + drow * 64 + ph1 * 8);
                oAcc[1][jd] = __builtin_amdgcn_mfma_f32_16x16x32_bf16(aPb, bVb, oAcc[1][jd], 0, 0, 0);
            }
            rsAcc[1] = __builtin_amdgcn_mfma_f32_16x16x32_bf16(aPa, vOnes, rsAcc[1], 0, 0, 0);
            rsAcc[1] = __builtin_amdgcn_mfma_f32_16x16x32_bf16(aPb, vOnes, rsAcc[1], 0, 0, 0);
            __builtin_amdgcn_s_setprio(0);
        }
    }

    // epilogue: rsAcc[g][r] = row sum for q=g*64+w*16+quad*4+r (repl. l16)
    const int bb = bh >> 4, h = bh & 15;
#pragma unroll
    for (int g = 0; g < 2; g++) {
        float inv[4];
#pragma unroll
        for (int r = 0; r < 4; r++) inv[r] = 1.0f / rsAcc[g][r];
#pragma unroll
        for (int jd = 0; jd < 4; jd++) {
            int d = jd * 16 + l16;
#pragma unroll
            for (int r = 0; r < 4; r++) {
                int s = q0 + g * 64 + w * 16 + quad * 4 + r;
                float v = oAcc[g][jd][r] * inv[r];
                o_ws[((size_t)bb * 2048 + s) * 1024 + h * 64 + d] = f2bf(v);
            }
        }
    }
}

// ---------- launch ----------
extern "C" void kernel_launch(void* const* d_in, const int* in_sizes, int n_in,
                              void* d_out, int out_size, void* d_ws, size_t ws_size,
                              hipStream_t stream) {
    const float* x  = (const float*)d_in[0];
    const float* Wq = (const float*)d_in[1];
    const float* bq = (const float*)d_in[2];
    const float* Wk = (const float*)d_in[3];
    const float* bk = (const float*)d_in[4];
    const float* Wv = (const float*)d_in[5];
    const float* bv = (const float*)d_in[6];
    const float* Wo = (const float*)d_in[7];
    const float* bo = (const float*)d_in[8];
    float* out = (float*)d_out;

    char* ws = (char*)d_ws;
    unsigned short* xb   = (unsigned short*)(ws);                       // 16 MB
    unsigned short* wqkv = (unsigned short*)(ws + (16ull << 20));       // 6 MB
    unsigned short* wo   = (unsigned short*)(ws + (22ull << 20));       // 2 MB
    float*          bqkv = (float*)(ws + (24ull << 20));                // 12 KB
    unsigned short* q_ws = (unsigned short*)(ws + (25ull << 20));       // 16 MB
    unsigned short* k_ws = (unsigned short*)(ws + (41ull << 20));       // 16 MB
    unsigned short* v_ws = (unsigned short*)(ws + (57ull << 20));       // 16 MB
    unsigned short* o_ws = xb;  // alias: x_bf dead after QKV GEMM

    // one cast kernel: 2097152 (x) + 1048576 (W) + 768 (bias) float4 slots
    cast_all_kernel<<<12291, 256, 0, stream>>>(x, Wq, Wk, Wv, Wo, bq, bk, bv,
                                               xb, wqkv, wo, bqkv);

    gemm128<0><<<dim3(64, 24), 256, 0, stream>>>(xb, wqkv, bqkv, q_ws, k_ws, v_ws, nullptr);
    attn_kernel<<<1024, 256, 0, stream>>>(q_ws, k_ws, v_ws, o_ws);
    gemm_oproj<<<dim3(64, 16), 256, 0, stream>>>(o_ws, wo, bo, out);
}

// Round 12
// 261.033 us; speedup vs baseline: 1.3907x; 1.0164x over previous
//
#include <hip/hip_runtime.h>
#include <stdint.h>

// ---------- types ----------
typedef __attribute__((ext_vector_type(8))) __bf16 bf16x8;
typedef __attribute__((ext_vector_type(4))) float floatx4;

#define DEV __device__ __forceinline__

DEV unsigned short f2bf(float f) {
    union { float f; unsigned u; } uf; uf.f = f;
    unsigned u = uf.u;
    unsigned r = (u + 0x7fffu + ((u >> 16) & 1u)) >> 16;  // RNE
    return (unsigned short)r;
}

DEV float fast_exp2(float x) {
#if __has_builtin(__builtin_amdgcn_exp2f)
    return __builtin_amdgcn_exp2f(x);
#else
    return exp2f(x);
#endif
}

DEV unsigned pack_trunc2(float lo, float hi) {
    // (trunc_bf16(hi) << 16) | trunc_bf16(lo) in one v_perm_b32
    return __builtin_amdgcn_perm(__float_as_uint(hi), __float_as_uint(lo), 0x07060302u);
}

DEV void async16(const void* g, void* l) {
    __builtin_amdgcn_global_load_lds(
        (const __attribute__((address_space(1))) void*)g,
        (__attribute__((address_space(3))) void*)l, 16, 0, 0);
}

// ---------- merged cast: x (8M f32), 4 weights (4M f32), 3 biases ----------
__global__ void cast_all_kernel(const float* __restrict__ x,
                                const float* __restrict__ Wq, const float* __restrict__ Wk,
                                const float* __restrict__ Wv, const float* __restrict__ Wo,
                                const float* __restrict__ bq, const float* __restrict__ bk,
                                const float* __restrict__ bv,
                                unsigned short* __restrict__ xb,
                                unsigned short* __restrict__ wqkv,
                                unsigned short* __restrict__ wo,
                                float* __restrict__ bqkv) {
    const int NX = 2097152;   // float4s in x
    const int NW = 262144;    // float4s per weight
    int i = blockIdx.x * blockDim.x + threadIdx.x;
    if (i < NX) {
        float4 v = reinterpret_cast<const float4*>(x)[i];
        ushort4 o;
        o.x = f2bf(v.x); o.y = f2bf(v.y); o.z = f2bf(v.z); o.w = f2bf(v.w);
        reinterpret_cast<ushort4*>(xb)[i] = o;
        return;
    }
    int j = i - NX;
    if (j < 4 * NW) {
        int seg = j >> 18, off = j & (NW - 1);
        const float* src = (seg == 0) ? Wq : (seg == 1) ? Wk : (seg == 2) ? Wv : Wo;
        unsigned short* dst = (seg < 3) ? (wqkv + seg * 1048576) : wo;
        float4 v = reinterpret_cast<const float4*>(src)[off];
        ushort4 o;
        o.x = f2bf(v.x); o.y = f2bf(v.y); o.z = f2bf(v.z); o.w = f2bf(v.w);
        reinterpret_cast<ushort4*>(dst)[off] = o;
        return;
    }
    int k = j - 4 * NW;
    if (k < 768) {  // 3 x 1024 floats of bias as float4
        int seg = k >> 8, off = k & 255;
        const float* src = (seg == 0) ? bq : (seg == 1) ? bk : bv;
        reinterpret_cast<float4*>(bqkv)[k] = reinterpret_cast<const float4*>(src)[off];
    }
}

// ---------- QKV GEMM: 256x128 tile, 512 threads (8 waves as 4x2) ----------
// C = A(8192x1024) * B(3072x1024)^T. Per-wave tile 64x64: acc/fragment/MFMA
// code identical to the verified 128x128 kernel; staging 4+2 async16/thread;
// same XOR-swizzle. Grid (32,24) = 768 blocks, 2 blocks/CU (LDS 48 KB,
// VGPR ~120). Arithmetic intensity 87 FLOP/B (was 65.5); L2 staging traffic
// 786 -> 590 MB.
// Epilogues: TWO sequential 128-row passes of the verified epilogue code
// (pass p: waves wr>>1==p stage sT; all 512 threads scatter).
// bn<8: Q (scaled by Dh^-0.5*log2e), 8..15: K, 16..23: V (round-0 perm).
// (Resubmission of round-11: container-level infra failure, no kernel
// verdict. Re-audited: bounds safe, all barriers convergent.)
__global__ __launch_bounds__(512)
void gemm256(const unsigned short* __restrict__ A,   // 8192 x 1024 (K-contig)
             const unsigned short* __restrict__ B,   // 3072 x 1024 (K-contig)
             const float* __restrict__ bias,         // 3072
             unsigned short* __restrict__ q_ws,
             unsigned short* __restrict__ k_ws,
             unsigned short* __restrict__ v_ws) {
    constexpr int K = 1024;
    __shared__ alignas(16) unsigned short smem[24576];  // 48 KB
    unsigned short* sA = smem;              // 256*64
    unsigned short* sB = smem + 256 * 64;   // 128*64
    unsigned short* sT = smem;              // 128*136 overlay (epilogue)

    const int tid = threadIdx.x;
    const int w = tid >> 6, lane = tid & 63, quad = lane >> 4, l16 = lane & 15;
    const int wr = w >> 1, wc = w & 1;      // wr in [0,4), wc in [0,2)
    const int bm = blockIdx.x, bn = blockIdx.y;
    const int arow0 = bm * 256, brow0 = bn * 128;

    floatx4 acc[4][4];
#pragma unroll
    for (int i = 0; i < 4; i++)
#pragma unroll
        for (int j = 0; j < 4; j++) acc[i][j] = (floatx4){0.f, 0.f, 0.f, 0.f};

    for (int k0 = 0; k0 < K; k0 += 64) {
#pragma unroll
        for (int i = 0; i < 4; i++) {   // A: 2048 chunks, 4/thread
            int ci = i * 512 + tid;
            int row = ci >> 3, cs = (ci & 7) ^ (row & 7);
            async16(A + (size_t)(arow0 + row) * K + k0 + cs * 8, (char*)sA + ci * 16);
        }
#pragma unroll
        for (int i = 0; i < 2; i++) {   // B: 1024 chunks, 2/thread
            int ci = i * 512 + tid;
            int row = ci >> 3, cs = (ci & 7) ^ (row & 7);
            async16(B + (size_t)(brow0 + row) * K + k0 + cs * 8, (char*)sB + ci * 16);
        }
        __syncthreads();
#pragma unroll
        for (int kk = 0; kk < 2; kk++) {
            bf16x8 aF[4], bF[4];
#pragma unroll
            for (int i = 0; i < 4; i++) {
                int row = wr * 64 + i * 16 + l16;
                int c = kk * 4 + quad, ph = c ^ (row & 7);
                aF[i] = *reinterpret_cast<const bf16x8*>(sA + row * 64 + ph * 8);
            }
#pragma unroll
            for (int j = 0; j < 4; j++) {
                int row = wc * 64 + j * 16 + l16;
                int c = kk * 4 + quad, ph = c ^ (row & 7);
                bF[j] = *reinterpret_cast<const bf16x8*>(sB + row * 64 + ph * 8);
            }
#pragma unroll
            for (int i = 0; i < 4; i++)
#pragma unroll
                for (int j = 0; j < 4; j++)
                    acc[i][j] = __builtin_amdgcn_mfma_f32_16x16x32_bf16(
                        aF[i], bF[j], acc[i][j], 0, 0, 0);
        }
        __syncthreads();
    }

    if (bn < 16) {
        // Q or K: two 128-row passes through sT, coalesced (bh, s, d) stores
        unsigned short* dst = (bn < 8) ? q_ws : k_ws;
        const float sc = (bn < 8) ? 0.18033688f : 1.0f;  // Dh^-0.5 * log2(e)
        const int nnbase = (bn & 7) * 128;
        const int c0 = (tid & 15) * 8;
        const int h = (nnbase + c0) >> 6, d = c0 & 63;
#pragma unroll
        for (int p = 0; p < 2; p++) {
            if (p) __syncthreads();
            if ((wr >> 1) == p) {
                const int wrl = wr & 1;
#pragma unroll
                for (int j = 0; j < 4; j++) {
                    const int c = wc * 64 + j * 16 + l16;
                    const float bia = bias[brow0 + c];
#pragma unroll
                    for (int i = 0; i < 4; i++) {
                        int s_loc = wrl * 64 + i * 16 + quad * 4;
#pragma unroll
                        for (int r = 0; r < 4; r++)
                            sT[(s_loc + r) * 136 + c] = f2bf((acc[i][j][r] + bia) * sc);
                    }
                }
            }
            __syncthreads();
#pragma unroll
            for (int it = 0; it < 4; it++) {
                int s_loc = (tid >> 4) + it * 32;
                int s = arow0 + p * 128 + s_loc;
                int bb = s >> 11, s4 = s & 2047;
                uint4 vdat = *reinterpret_cast<const uint4*>(sT + s_loc * 136 + c0);
                *reinterpret_cast<uint4*>(
                    dst + ((size_t)(bb * 16 + h) * 2048 + s4) * 64 + d) = vdat;
            }
        }
    } else {
        // V: two 128-row passes; round-0 verified 64-key perm
        // v = wrl*64 + (quad*4+r)*4 + i; store (bh, d, s_virtual) coalesced
        const int chunk = tid & 15;
#pragma unroll
        for (int p = 0; p < 2; p++) {
            if (p) __syncthreads();
            if ((wr >> 1) == p) {
                const int wrl = wr & 1;
#pragma unroll
                for (int j = 0; j < 4; j++) {
                    const int c = wc * 64 + j * 16 + l16;  // block-local col
                    const float bia = bias[brow0 + c];
#pragma unroll
                    for (int i = 0; i < 4; i++) {
#pragma unroll
                        for (int r = 0; r < 4; r++) {
                            int v = wrl * 64 + (quad * 4 + r) * 4 + i;
                            sT[c * 136 + v] = f2bf(acc[i][j][r] + bia);
                        }
                    }
                }
            }
            __syncthreads();
            const int sblk = bm * 2 + p;          // 128-row block idx [0,64)
            const int bb2 = sblk >> 4, blk = sblk & 15;
#pragma unroll
            for (int it = 0; it < 4; it++) {
                int row = (tid >> 4) + it * 32;   // block-local col 0..127
                int h = (bn - 16) * 2 + (row >> 6), d = row & 63;
                ushort4 lo = *reinterpret_cast<const ushort4*>(sT + row * 136 + chunk * 8);
                ushort4 hi = *reinterpret_cast<const ushort4*>(sT + row * 136 + chunk * 8 + 4);
                size_t off = ((size_t)(bb2 * 16 + h) * 64 + d) * 2048 + blk * 128 + chunk * 8;
                *reinterpret_cast<ushort4*>(v_ws + off) = lo;
                *reinterpret_cast<ushort4*>(v_ws + off + 4) = hi;
            }
        }
    }
}

// ---------- out-proj GEMM: 128x64 tile, grid (64,16) = 1024 blocks ----------
// M=8192, N=1024, K=1024. 4+ blocks/CU fully resident, one generation.
__global__ __launch_bounds__(256)
void gemm_oproj(const unsigned short* __restrict__ A,   // 8192 x 1024
                const unsigned short* __restrict__ Bw,  // 1024 x 1024
                const float* __restrict__ bias,         // 1024
                float* __restrict__ fout) {
    constexpr int K = 1024;
    __shared__ alignas(16) unsigned short smem[192 * 64];  // 24 KB
    unsigned short* sA = smem;             // 128*64
    unsigned short* sB = smem + 128 * 64;  // 64*64
    float* sT32 = reinterpret_cast<float*>(smem);  // 64*68 f32 = 17408 B

    const int tid = threadIdx.x;
    const int w = tid >> 6, lane = tid & 63, quad = lane >> 4, l16 = lane & 15;
    const int wr = w >> 1, wc = w & 1;
    const int bm = blockIdx.x, bn = blockIdx.y;
    const int arow0 = bm * 128, brow0 = bn * 64;

    floatx4 acc[4][2];
#pragma unroll
    for (int i = 0; i < 4; i++)
#pragma unroll
        for (int j = 0; j < 2; j++) acc[i][j] = (floatx4){0.f, 0.f, 0.f, 0.f};

    for (int k0 = 0; k0 < K; k0 += 64) {
#pragma unroll
        for (int i = 0; i < 4; i++) {  // A: 1024 chunks, 4/thread
            int ci = i * 256 + tid;
            int row = ci >> 3, cs = (ci & 7) ^ (row & 7);
            async16(A + (size_t)(arow0 + row) * K + k0 + cs * 8, (char*)sA + ci * 16);
        }
#pragma unroll
        for (int i = 0; i < 2; i++) {  // B: 512 chunks, 2/thread
            int ci = i * 256 + tid;
            int row = ci >> 3, cs = (ci & 7) ^ (row & 7);
            async16(Bw + (size_t)(brow0 + row) * K + k0 + cs * 8, (char*)sB + ci * 16);
        }
        __syncthreads();
#pragma unroll
        for (int kk = 0; kk < 2; kk++) {
            bf16x8 aF[4], bF[2];
#pragma unroll
            for (int i = 0; i < 4; i++) {
                int row = wr * 64 + i * 16 + l16;
                int ph = (kk * 4 + quad) ^ (row & 7);
                aF[i] = *reinterpret_cast<const bf16x8*>(sA + row * 64 + ph * 8);
            }
#pragma unroll
            for (int j = 0; j < 2; j++) {
                int row = wc * 32 + j * 16 + l16;
                int ph = (kk * 4 + quad) ^ (row & 7);
                bF[j] = *reinterpret_cast<const bf16x8*>(sB + row * 64 + ph * 8);
            }
#pragma unroll
            for (int i = 0; i < 4; i++)
#pragma unroll
                for (int j = 0; j < 2; j++)
                    acc[i][j] = __builtin_amdgcn_mfma_f32_16x16x32_bf16(
                        aF[i], bF[j], acc[i][j], 0, 0, 0);
        }
        __syncthreads();
    }

    // epilogue: fp32 out via LDS transpose, two 64-row chunks
#pragma unroll
    for (int ch = 0; ch < 2; ch++) {
        if (ch) __syncthreads();
        if (wr == ch) {
#pragma unroll
            for (int j = 0; j < 2; j++) {
                const int c = wc * 32 + j * 16 + l16;
                const float bia = bias[brow0 + c];
#pragma unroll
                for (int i = 0; i < 4; i++) {
                    int s_loc = i * 16 + quad * 4;
#pragma unroll
                    for (int r = 0; r < 4; r++)
                        sT32[(s_loc + r) * 68 + c] = acc[i][j][r] + bia;
                }
            }
        }
        __syncthreads();
        const int cpos = (tid & 15) * 4;
#pragma unroll
        for (int it = 0; it < 4; it++) {
            int s_loc = (tid >> 4) + it * 16;
            int grow = arow0 + ch * 64 + s_loc;
            float4 vv = *reinterpret_cast<const float4*>(sT32 + s_loc * 68 + cpos);
            *reinterpret_cast<float4*>(fout + (size_t)grow * 1024 + brow0 + cpos) = vv;
        }
    }
}

// ---------- flash attention: one block = (bh, 128 q rows) ----------
// ROUND-10 EXACT BODY (best measured: 83.3 us): no per-tile lgkmcnt walls
// (same-wave DS FIFO + compiler may-alias ordering), T5 setprio on MFMA
// clusters. LDS 40 KB, 4 blocks/CU (grid-limited: 1024 blocks = 4/CU).
__global__ __launch_bounds__(256, 4)
void attn_kernel(const unsigned short* __restrict__ q_ws,
                 const unsigned short* __restrict__ k_ws,
                 const unsigned short* __restrict__ v_ws,
                 unsigned short* __restrict__ o_ws) {
    __shared__ alignas(16) unsigned short smem[20480];  // 40 KB
    // [0,4096): sK buf0   [4096,8192): sK buf1
    // [8192,12288): sVt buf0  [12288,16384): sVt buf1
    // [16384,20480): sP, wave w at +w*1024 (16 q-rows x 64 vkeys, chunk-XOR)

    const int tid = threadIdx.x;
    const int w = tid >> 6, lane = tid & 63, quad = lane >> 4, l16 = lane & 15;
    // XCD-affinity remap: all 16 q-blocks of one bh land on one XCD (id%8)
    const int id = blockIdx.x;
    const int bh = (id >> 7) * 8 + (id & 7);
    const int q0 = ((id >> 3) & 15) * 128;
    const size_t base = (size_t)bh * 2048 * 64;

    unsigned short* sPw = smem + 16384 + w * 1024;

    bf16x8 aQ[2][2];
#pragma unroll
    for (int g = 0; g < 2; g++) {
        int qrow = q0 + g * 64 + w * 16 + l16;
        const unsigned short* qp = q_ws + base + (size_t)qrow * 64 + quad * 8;
        aQ[g][0] = *reinterpret_cast<const bf16x8*>(qp);
        aQ[g][1] = *reinterpret_cast<const bf16x8*>(qp + 32);
    }

    // staging: 64x64 tile = 512 chunks of 16B; 2 chunks per thread for K and V
    const unsigned short* kg[2];
    const unsigned short* vg[2];
    int loff[2];
#pragma unroll
    for (int it = 0; it < 2; it++) {
        int ci = it * 256 + tid;
        int row = ci >> 3, cl = ci & 7, cs = cl ^ (row & 7);
        kg[it] = k_ws + base + (size_t)row * 64 + cs * 8;
        vg[it] = v_ws + base + (size_t)row * 2048 + cs * 8;
        loff[it] = ci * 8;  // shorts
    }

    const __bf16 one = (__bf16)1.0f;
    const bf16x8 vOnes = {one, one, one, one, one, one, one, one};

    floatx4 oAcc[2][4], rsAcc[2];
#pragma unroll
    for (int g = 0; g < 2; g++) {
#pragma unroll
        for (int j = 0; j < 4; j++) oAcc[g][j] = (floatx4){0.f, 0.f, 0.f, 0.f};
        rsAcc[g] = (floatx4){0.f, 0.f, 0.f, 0.f};
    }

    // prologue: stage tile 0 into buf 0
    {
#pragma unroll
        for (int it = 0; it < 2; it++) {
            async16(kg[it], smem + loff[it]);
            async16(vg[it], smem + 8192 + loff[it]);
        }
    }

    const int xr = l16 & 7;
    const int offw0 = l16 * 64 + (((2 * quad) ^ xr) << 3);
    const int offw1 = l16 * 64 + (((2 * quad + 1) ^ xr) << 3);
    const int offr0 = l16 * 64 + ((quad ^ xr) << 3);
    const int offr1 = l16 * 64 + (((4 + quad) ^ xr) << 3);

    for (int t = 0; t < 32; t++) {
        const int b = t & 1;
        const unsigned short* sK = smem + b * 4096;
        const unsigned short* sVt = smem + 8192 + b * 4096;
        __syncthreads();  // tile t staged (vmcnt drain); buf b^1 free for reuse

        if (t < 31) {
            const int kv0 = (t + 1) * 64;
            unsigned short* dK = smem + (b ^ 1) * 4096;
            unsigned short* dV = smem + 8192 + (b ^ 1) * 4096;
#pragma unroll
            for (int it = 0; it < 2; it++) {
                async16(kg[it] + (size_t)kv0 * 64, dK + loff[it]);
                async16(vg[it] + kv0, dV + loff[it]);
            }
        }

        // S'^T = K Q'^T for BOTH groups, sharing each aK load.
        floatx4 s0[4], s1[4];
#pragma unroll
        for (int j = 0; j < 4; j++) {
            s0[j] = (floatx4){0.f, 0.f, 0.f, 0.f};
            s1[j] = (floatx4){0.f, 0.f, 0.f, 0.f};
        }
        __builtin_amdgcn_s_setprio(1);
#pragma unroll
        for (int kk = 0; kk < 2; kk++) {
#pragma unroll
            for (int j = 0; j < 4; j++) {
                int krow = j * 16 + l16;
                int ph = (kk * 4 + quad) ^ (krow & 7);
                bf16x8 aK = *reinterpret_cast<const bf16x8*>(sK + krow * 64 + ph * 8);
                s0[j] = __builtin_amdgcn_mfma_f32_16x16x32_bf16(aK, aQ[0][kk], s0[j], 0, 0, 0);
                s1[j] = __builtin_amdgcn_mfma_f32_16x16x32_bf16(aK, aQ[1][kk], s1[j], 0, 0, 0);
            }
        }
        __builtin_amdgcn_s_setprio(0);

        // group 0: exp, pack, write sP0 (same-wave DS order: write < read)
#pragma unroll
        for (int j = 0; j < 4; j++)
#pragma unroll
            for (int r = 0; r < 4; r++) s0[j][r] = fast_exp2(s0[j][r]);
        {
            uint4 w0, w1;
            w0.x = pack_trunc2(s0[0][0], s0[1][0]);
            w0.y = pack_trunc2(s0[2][0], s0[3][0]);
            w0.z = pack_trunc2(s0[0][1], s0[1][1]);
            w0.w = pack_trunc2(s0[2][1], s0[3][1]);
            w1.x = pack_trunc2(s0[0][2], s0[1][2]);
            w1.y = pack_trunc2(s0[2][2], s0[3][2]);
            w1.z = pack_trunc2(s0[0][3], s0[1][3]);
            w1.w = pack_trunc2(s0[2][3], s0[3][3]);
            *reinterpret_cast<uint4*>(sPw + offw0) = w0;
            *reinterpret_cast<uint4*>(sPw + offw1) = w1;
        }

        // group 0: read aP0, PV0, rowsum0
        {
            bf16x8 aPa = *reinterpret_cast<const bf16x8*>(sPw + offr0);
            bf16x8 aPb = *reinterpret_cast<const bf16x8*>(sPw + offr1);
            __builtin_amdgcn_s_setprio(1);
#pragma unroll
            for (int jd = 0; jd < 4; jd++) {
                int drow = jd * 16 + l16;
                int ph0 = quad ^ (drow & 7);
                bf16x8 bVa = *reinterpret_cast<const bf16x8*>(sVt + drow * 64 + ph0 * 8);
                oAcc[0][jd] = __builtin_amdgcn_mfma_f32_16x16x32_bf16(aPa, bVa, oAcc[0][jd], 0, 0, 0);
                int ph1 = (4 + quad) ^ (drow & 7);
                bf16x8 bVb = *reinterpret_cast<const bf16x8*>(sVt + drow * 64 + ph1 * 8);
                oAcc[0][jd] = __builtin_amdgcn_mfma_f32_16x16x32_bf16(aPb, bVb, oAcc[0][jd], 0, 0, 0);
            }
            rsAcc[0] = __builtin_amdgcn_mfma_f32_16x16x32_bf16(aPa, vOnes, rsAcc[0], 0, 0, 0);
            rsAcc[0] = __builtin_amdgcn_mfma_f32_16x16x32_bf16(aPb, vOnes, rsAcc[0], 0, 0, 0);
            __builtin_amdgcn_s_setprio(0);
        }

        // group 1: exp, pack, write sP1 (after group-0 reads by program
        // order + may-alias; same-wave DS FIFO preserves it in HW)
#pragma unroll
        for (int j = 0; j < 4; j++)
#pragma unroll
            for (int r = 0; r < 4; r++) s1[j][r] = fast_exp2(s1[j][r]);
        {
            uint4 w0, w1;
            w0.x = pack_trunc2(s1[0][0], s1[1][0]);
            w0.y = pack_trunc2(s1[2][0], s1[3][0]);
            w0.z = pack_trunc2(s1[0][1], s1[1][1]);
            w0.w = pack_trunc2(s1[2][1], s1[3][1]);
            w1.x = pack_trunc2(s1[0][2], s1[1][2]);
            w1.y = pack_trunc2(s1[2][2], s1[3][2]);
            w1.z = pack_trunc2(s1[0][3], s1[1][3]);
            w1.w = pack_trunc2(s1[2][3], s1[3][3]);
            *reinterpret_cast<uint4*>(sPw + offw0) = w0;
            *reinterpret_cast<uint4*>(sPw + offw1) = w1;
        }

        // group 1: read aP1, PV1, rowsum1
        {
            bf16x8 aPa = *reinterpret_cast<const bf16x8*>(sPw + offr0);
            bf16x8 aPb = *reinterpret_cast<const bf16x8*>(sPw + offr1);
            __builtin_amdgcn_s_setprio(1);
#pragma unroll
            for (int jd = 0; jd < 4; jd++) {
                int drow = jd * 16 + l16;
                int ph0 = quad ^ (drow & 7);
                bf16x8 bVa = *reinterpret_cast<const bf16x8*>(sVt + drow * 64 + ph0 * 8);
                oAcc[1][jd] = __builtin_amdgcn_mfma_f32_16x16x32_bf16(aPa, bVa, oAcc[1][jd], 0, 0, 0);
                int ph1 = (4 + quad) ^ (drow & 7);
                bf16x8 bVb = *reinterpret_cast<const bf16x8*>(sVt + drow * 64 + ph1 * 8);
                oAcc[1][jd] = __builtin_amdgcn_mfma_f32_16x16x32_bf16(aPb, bVb, oAcc[1][jd], 0, 0, 0);
            }
            rsAcc[1] = __builtin_amdgcn_mfma_f32_16x16x32_bf16(aPa, vOnes, rsAcc[1], 0, 0, 0);
            rsAcc[1] = __builtin_amdgcn_mfma_f32_16x16x32_bf16(aPb, vOnes, rsAcc[1], 0, 0, 0);
            __builtin_amdgcn_s_setprio(0);
        }
    }

    // epilogue: rsAcc[g][r] = row sum for q=g*64+w*16+quad*4+r (repl. l16)
    const int bb = bh >> 4, h = bh & 15;
#pragma unroll
    for (int g = 0; g < 2; g++) {
        float inv[4];
#pragma unroll
        for (int r = 0; r < 4; r++) inv[r] = 1.0f / rsAcc[g][r];
#pragma unroll
        for (int jd = 0; jd < 4; jd++) {
            int d = jd * 16 + l16;
#pragma unroll
            for (int r = 0; r < 4; r++) {
                int s = q0 + g * 64 + w * 16 + quad * 4 + r;
                float v = oAcc[g][jd][r] * inv[r];
                o_ws[((size_t)bb * 2048 + s) * 1024 + h * 64 + d] = f2bf(v);
            }
        }
    }
}

// ---------- launch ----------
extern "C" void kernel_launch(void* const* d_in, const int* in_sizes, int n_in,
                              void* d_out, int out_size, void* d_ws, size_t ws_size,
                              hipStream_t stream) {
    const float* x  = (const float*)d_in[0];
    const float* Wq = (const float*)d_in[1];
    const float* bq = (const float*)d_in[2];
    const float* Wk = (const float*)d_in[3];
    const float* bk = (const float*)d_in[4];
    const float* Wv = (const float*)d_in[5];
    const float* bv = (const float*)d_in[6];
    const float* Wo = (const float*)d_in[7];
    const float* bo = (const float*)d_in[8];
    float* out = (float*)d_out;

    char* ws = (char*)d_ws;
    unsigned short* xb   = (unsigned short*)(ws);                       // 16 MB
    unsigned short* wqkv = (unsigned short*)(ws + (16ull << 20));       // 6 MB
    unsigned short* wo   = (unsigned short*)(ws + (22ull << 20));       // 2 MB
    float*          bqkv = (float*)(ws + (24ull << 20));                // 12 KB
    unsigned short* q_ws = (unsigned short*)(ws + (25ull << 20));       // 16 MB
    unsigned short* k_ws = (unsigned short*)(ws + (41ull << 20));       // 16 MB
    unsigned short* v_ws = (unsigned short*)(ws + (57ull << 20));       // 16 MB
    unsigned short* o_ws = xb;  // alias: x_bf dead after QKV GEMM

    // one cast kernel: 2097152 (x) + 1048576 (W) + 768 (bias) float4 slots
    cast_all_kernel<<<12291, 256, 0, stream>>>(x, Wq, Wk, Wv, Wo, bq, bk, bv,
                                               xb, wqkv, wo, bqkv);

    gemm256<<<dim3(32, 24), 512, 0, stream>>>(xb, wqkv, bqkv, q_ws, k_ws, v_ws);
    attn_kernel<<<1024, 256, 0, stream>>>(q_ws, k_ws, v_ws, o_ws);
    gemm_oproj<<<dim3(64, 16), 256, 0, stream>>>(o_ws, wo, bo, out);
}